// Round 1
// baseline (5564.838 us; speedup 1.0000x reference)
//
#include <hip/hip_runtime.h>
#include <cstdint>

#define HID 128

static constexpr int kNOp = 50000, kNMa = 1000, kNJob = 5000;
static constexpr int kEsz[5]  = {150000, 100000, 150000, 100000, 100000};
static constexpr int kSrcT[5] = {0, 0, 1, 2, 0};
static constexpr int kDstT[5] = {0, 1, 0, 0, 2};
static constexpr int kNNode[3] = {kNOp, kNMa, kNJob};
static constexpr int kKin[3]   = {64, 32, 16};

// ---------------------------------------------------------------- GEMM (fp32)
// C[M x N] = A[M x K] @ B[K x N] (+bias). N multiple of 64, K multiple of 16.
__global__ __launch_bounds__(256) void gemm_f32(
    const float* __restrict__ A, const float* __restrict__ B,
    const float* __restrict__ bias, float* __restrict__ C,
    int M, int N, int K) {
  __shared__ float As[16][65];
  __shared__ float Bs[16][64];
  const int bm = blockIdx.y * 64, bn = blockIdx.x * 64;
  const int tid = threadIdx.x;
  const int tr = tid >> 4, tc = tid & 15;
  float acc[4][4] = {};
  for (int k0 = 0; k0 < K; k0 += 16) {
    {
      int r = tid >> 2, kk = (tid & 3) * 4;
      int row = bm + r;
      float4 v = make_float4(0.f, 0.f, 0.f, 0.f);
      if (row < M) v = *(const float4*)(A + (size_t)row * K + k0 + kk);
      As[kk + 0][r] = v.x; As[kk + 1][r] = v.y;
      As[kk + 2][r] = v.z; As[kk + 3][r] = v.w;
    }
    {
      int r = tid >> 4, c = (tid & 15) * 4;
      float4 v = *(const float4*)(B + (size_t)(k0 + r) * N + bn + c);
      *(float4*)&Bs[r][c] = v;
    }
    __syncthreads();
#pragma unroll
    for (int kk = 0; kk < 16; kk++) {
      float a[4], b[4];
#pragma unroll
      for (int i = 0; i < 4; i++) a[i] = As[kk][tr * 4 + i];
#pragma unroll
      for (int j = 0; j < 4; j++) b[j] = Bs[kk][tc * 4 + j];
#pragma unroll
      for (int i = 0; i < 4; i++)
#pragma unroll
        for (int j = 0; j < 4; j++) acc[i][j] += a[i] * b[j];
    }
    __syncthreads();
  }
#pragma unroll
  for (int i = 0; i < 4; i++) {
    int row = bm + tr * 4 + i;
    if (row >= M) continue;
    int col = bn + tc * 4;
    float4 v;
    v.x = acc[i][0]; v.y = acc[i][1]; v.z = acc[i][2]; v.w = acc[i][3];
    if (bias) { v.x += bias[col]; v.y += bias[col + 1]; v.z += bias[col + 2]; v.w += bias[col + 3]; }
    *(float4*)(C + (size_t)row * N + col) = v;
  }
}

// ------------------------------------------------- fold attention vectors
// For each (l,t,h): S[k] = sum_c Wg[k][hC+c]*att_s[hC+c]; D likewise with att_d;
// v[k] = sum_c Wge[k][hC+c]*att_e[hC+c]; w32[m] = sum_k We_proj[t][m][k]*v[k];
// cvec = sum_k be_proj[t][k]*v[k].
__global__ void fold_kernel(const float* __restrict__ Wg, const float* __restrict__ att_s,
                            const float* __restrict__ att_d, const float* __restrict__ Wge,
                            const float* __restrict__ att_e, const float* __restrict__ Wep,
                            const float* __restrict__ bep,
                            float* __restrict__ S, float* __restrict__ D,
                            float* __restrict__ w32, float* __restrict__ cvec) {
  int idx = blockIdx.x;          // (l*5+t)*8 + h
  int h = idx & 7, lt = idx >> 3;
  int l = lt / 5, t = lt % 5;
  int H = (l < 2) ? 8 : 1, C = HID / H;
  if (h >= H) return;
  int k = threadIdx.x;           // 0..127
  const float* wg  = Wg  + (size_t)lt * HID * HID;
  const float* wge = Wge + (size_t)lt * HID * HID;
  const float* as_ = att_s + (size_t)lt * HID + h * C;
  const float* ad_ = att_d + (size_t)lt * HID + h * C;
  const float* ae_ = att_e + (size_t)lt * HID + h * C;
  float s = 0.f, d = 0.f, v = 0.f;
  for (int c = 0; c < C; c++) {
    float wr = wg[(size_t)k * HID + h * C + c];
    s += wr * as_[c];
    d += wr * ad_[c];
    v += wge[(size_t)k * HID + h * C + c] * ae_[c];
  }
  S[(size_t)idx * HID + k] = s;
  D[(size_t)idx * HID + k] = d;
  __shared__ float vs[HID];
  vs[k] = v;
  __syncthreads();
  if (k < 32) {
    const float* wp = Wep + (size_t)t * 32 * HID + (size_t)k * HID;
    float a = 0.f;
    for (int j = 0; j < HID; j++) a += wp[j] * vs[j];
    w32[(size_t)idx * 32 + k] = a;
  }
  if (k == 32) {
    const float* bp = bep + (size_t)t * HID;
    float a = 0.f;
    for (int j = 0; j < HID; j++) a += bp[j] * vs[j];
    cvec[idx] = a;
  }
}

// -------------------------------------------- a_s/a_d: out[n,h] = x[n,:]·V[h,:]
template <int H>
__global__ void rowdot(const float* __restrict__ x, const float* __restrict__ V,
                       float* __restrict__ out, int N) {
  int lane = threadIdx.x & 63;
  int node = (int)((blockIdx.x * (size_t)blockDim.x + threadIdx.x) >> 6);
  if (node >= N) return;
  float2 xv = ((const float2*)(x + (size_t)node * HID))[lane];
  float acc[H];
#pragma unroll
  for (int h = 0; h < H; h++) {
    float2 vv = ((const float2*)(V + (size_t)h * HID))[lane];
    acc[h] = xv.x * vv.x + xv.y * vv.y;
  }
#pragma unroll
  for (int off = 32; off; off >>= 1)
#pragma unroll
    for (int h = 0; h < H; h++) acc[h] += __shfl_xor(acc[h], off, 64);
  if (lane == 0) {
#pragma unroll
    for (int h = 0; h < H; h++) out[(size_t)node * H + h] = acc[h];
  }
}

__device__ inline unsigned int enc_f32(float f) {
  unsigned int b = __float_as_uint(f);
  return (b & 0x80000000u) ? ~b : (b | 0x80000000u);
}
__device__ inline float dec_f32(unsigned int u) {
  unsigned int b = (u & 0x80000000u) ? (u & 0x7FFFFFFFu) : ~u;
  return __uint_as_float(b);
}

// ----------------------------- pass A: logits + segment max (int-encoded)
template <int H>
__global__ void pass_a(const int* __restrict__ src, const int* __restrict__ dst,
                       const float* __restrict__ a_s, const float* __restrict__ a_d,
                       const float* __restrict__ ea, const float* __restrict__ w32,
                       const float* __restrict__ cvec, int E,
                       float* __restrict__ logits, unsigned int* __restrict__ m) {
  __shared__ float w[H][32];
  __shared__ float cc[H];
  for (int i = threadIdx.x; i < H * 32; i += blockDim.x) {
    int h = i >> 5, k = i & 31;
    w[h][k] = w32[h * 32 + k];
  }
  if (threadIdx.x < H) cc[threadIdx.x] = cvec[threadIdx.x];
  __syncthreads();
  int e = blockIdx.x * blockDim.x + threadIdx.x;
  if (e >= E) return;
  int s = src[e], d = dst[e];
  float x[32];
  const float4* p = (const float4*)(ea + (size_t)e * 32);
#pragma unroll
  for (int i = 0; i < 8; i++) {
    float4 v = p[i];
    x[4 * i] = v.x; x[4 * i + 1] = v.y; x[4 * i + 2] = v.z; x[4 * i + 3] = v.w;
  }
#pragma unroll
  for (int h = 0; h < H; h++) {
    float a = cc[h];
#pragma unroll
    for (int k = 0; k < 32; k++) a += x[k] * w[h][k];
    float v = a + a_s[(size_t)s * H + h] + a_d[(size_t)d * H + h];
    v = v > 0.f ? v : 0.2f * v;
    logits[(size_t)h * E + e] = v;
    atomicMax(&m[(size_t)d * H + h], enc_f32(v));
  }
}

// ------------------------------ pass B1: ex = exp(logit - max), sum to den
template <int H>
__global__ void pass_b1(const int* __restrict__ dst, float* __restrict__ logits,
                        const unsigned int* __restrict__ m, float* __restrict__ den, int E) {
  int e = blockIdx.x * blockDim.x + threadIdx.x;
  if (e >= E) return;
  int d = dst[e];
#pragma unroll
  for (int h = 0; h < H; h++) {
    float mv = dec_f32(m[(size_t)d * H + h]);
    float ex = expf(logits[(size_t)h * E + e] - mv);
    logits[(size_t)h * E + e] = ex;
    unsafeAtomicAdd(&den[(size_t)d * H + h], ex);
  }
}

// ------------------- pass B2: agg[dst] += (ex/den) * xs[src]  (32 lanes/edge)
template <int H>
__global__ void pass_b2(const int* __restrict__ src, const int* __restrict__ dst,
                        const float* __restrict__ ex, const float* __restrict__ den,
                        const float* __restrict__ xs, float* __restrict__ agg, int E) {
  int lane = threadIdx.x & 31;
  size_t gt = blockIdx.x * (size_t)blockDim.x + threadIdx.x;
  int e = (int)(gt >> 5);
  if (e >= E) return;
  int s = src[e], d = dst[e];
  constexpr int C = HID / H;
  int c0 = lane * 4;
  int h = c0 / C;
  float w = ex[(size_t)h * E + e] / (den[(size_t)d * H + h] + 1e-16f);
  float4 xv = *(const float4*)(xs + (size_t)s * HID + c0);
  float* ap = agg + (size_t)d * HID + c0;
  unsafeAtomicAdd(ap + 0, w * xv.x);
  unsafeAtomicAdd(ap + 1, w * xv.y);
  unsafeAtomicAdd(ap + 2, w * xv.z);
  unsafeAtomicAdd(ap + 3, w * xv.w);
}

// ------------------------------------------------- BatchNorm column stats
__global__ void colstats(const float* __restrict__ h, int N, float* __restrict__ stats) {
  int tid = threadIdx.x;
  int col = tid & 127, half = tid >> 7;
  float s = 0.f, q = 0.f;
  for (int r = blockIdx.x * 2 + half; r < N; r += gridDim.x * 2) {
    float v = h[(size_t)r * HID + col];
    s += v; q += v * v;
  }
  __shared__ float ls[256], lq[256];
  ls[tid] = s; lq[tid] = q;
  __syncthreads();
  if (tid < 128) {
    s = ls[tid] + ls[tid + 128];
    q = lq[tid] + lq[tid + 128];
    unsafeAtomicAdd(&stats[col], s);
    unsafeAtomicAdd(&stats[128 + col], q);
  }
}

// ------------------------------- BN apply + optional ReLU + residual
__global__ void bn_apply(const float* __restrict__ agg, const float* __restrict__ xold,
                         float* __restrict__ xnew, const float* __restrict__ stats, int N,
                         const float* __restrict__ gamma, const float* __restrict__ beta,
                         int relu) {
  size_t i = blockIdx.x * (size_t)blockDim.x + threadIdx.x;
  if (i >= (size_t)N * 32) return;
  int c4 = ((int)(i & 31)) * 4;
  float invN = 1.0f / (float)N;
  float4 av = ((const float4*)agg)[i];
  float4 xv = ((const float4*)xold)[i];
  float a[4] = {av.x, av.y, av.z, av.w};
  float xo[4] = {xv.x, xv.y, xv.z, xv.w};
  float o[4];
#pragma unroll
  for (int j = 0; j < 4; j++) {
    int c = c4 + j;
    float mu = stats[c] * invN;
    float var = stats[128 + c] * invN - mu * mu;
    float g = gamma[c] * rsqrtf(var + 1e-5f);
    float v = (a[j] - mu) * g + beta[c];
    if (relu) v = fmaxf(v, 0.f);
    o[j] = v + xo[j];
  }
  ((float4*)xnew)[i] = make_float4(o[0], o[1], o[2], o[3]);
}

// ============================================================== host driver
extern "C" void kernel_launch(void* const* d_in, const int* in_sizes, int n_in,
                              void* d_out, int out_size, void* d_ws, size_t ws_size,
                              hipStream_t stream) {
  const float* x_in[3] = {(const float*)d_in[0], (const float*)d_in[1], (const float*)d_in[2]};
  const int* ei[5];
  const float* ea[5];
  for (int t = 0; t < 5; t++) {
    ei[t] = (const int*)d_in[3 + 2 * t];
    ea[t] = (const float*)d_in[4 + 2 * t];
  }
  const float* Wn[3]  = {(const float*)d_in[13], (const float*)d_in[15], (const float*)d_in[17]};
  const float* bnb[3] = {(const float*)d_in[14], (const float*)d_in[16], (const float*)d_in[18]};
  const float* Wep   = (const float*)d_in[19];
  const float* bep   = (const float*)d_in[20];
  const float* Wg    = (const float*)d_in[21];
  const float* att_s = (const float*)d_in[22];
  const float* att_d = (const float*)d_in[23];
  const float* Wge   = (const float*)d_in[24];
  const float* att_e = (const float*)d_in[25];
  // d_in[26] = bg: provably cancelled by BatchNorm mean-subtraction; unused.
  const float* gamma = (const float*)d_in[27];
  const float* beta  = (const float*)d_in[28];
  const float* Wo    = (const float*)d_in[29];
  const float* bo    = (const float*)d_in[30];

  float* ws = (float*)d_ws;
  size_t off = 0;
  auto alloc = [&](size_t n) { size_t o = off; off += (n + 255) & ~(size_t)255; return o; };

  float* xbuf[2][3];
  float* agg[3];
  for (int b = 0; b < 2; b++)
    for (int nt = 0; nt < 3; nt++) xbuf[b][nt] = ws + alloc((size_t)kNNode[nt] * HID);
  for (int nt = 0; nt < 3; nt++) agg[nt] = ws + alloc((size_t)kNNode[nt] * HID);
  float* xs      = ws + alloc((size_t)kNOp * HID);
  float* as_     = ws + alloc((size_t)kNOp * 8);
  float* ad_     = ws + alloc((size_t)kNOp * 8);
  float* logits  = ws + alloc((size_t)150000 * 8);
  unsigned int* mbuf = (unsigned int*)(ws + alloc((size_t)kNOp * 8));
  float* den     = ws + alloc((size_t)kNOp * 8);
  float* Sv      = ws + alloc((size_t)3 * 5 * 8 * HID);
  float* Dv      = ws + alloc((size_t)3 * 5 * 8 * HID);
  float* w32     = ws + alloc((size_t)3 * 5 * 8 * 32);
  float* cv      = ws + alloc((size_t)3 * 5 * 8);
  float* stats   = ws + alloc((size_t)3 * 256);
  (void)ws_size; (void)in_sizes; (void)n_in; (void)out_size;

  float *xcur[3], *xnxt[3];
  for (int nt = 0; nt < 3; nt++) { xcur[nt] = xbuf[0][nt]; xnxt[nt] = xbuf[1][nt]; }

  // node input projections
  for (int nt = 0; nt < 3; nt++) {
    dim3 g(HID / 64, (kNNode[nt] + 63) / 64);
    gemm_f32<<<g, 256, 0, stream>>>(x_in[nt], Wn[nt], bnb[nt], xcur[nt], kNNode[nt], HID, kKin[nt]);
  }
  fold_kernel<<<120, 128, 0, stream>>>(Wg, att_s, att_d, Wge, att_e, Wep, bep, Sv, Dv, w32, cv);

  for (int l = 0; l < 3; l++) {
    int H = (l < 2) ? 8 : 1;
    for (int nt = 0; nt < 3; nt++)
      hipMemsetAsync(agg[nt], 0, (size_t)kNNode[nt] * HID * 4, stream);
    for (int t = 0; t < 5; t++) {
      int st = kSrcT[t], dt = kDstT[t], E = kEsz[t];
      int ns = kNNode[st], nd = kNNode[dt];
      int idx0 = (l * 5 + t) * 8;
      dim3 g(HID / 64, (ns + 63) / 64);
      gemm_f32<<<g, 256, 0, stream>>>(xcur[st], Wg + (size_t)(l * 5 + t) * HID * HID, nullptr,
                                      xs, ns, HID, HID);
      hipMemsetAsync(mbuf, 0, (size_t)nd * H * 4, stream);
      hipMemsetAsync(den, 0, (size_t)nd * H * 4, stream);
      if (H == 8) {
        rowdot<8><<<(ns + 3) / 4, 256, 0, stream>>>(xcur[st], Sv + (size_t)idx0 * HID, as_, ns);
        rowdot<8><<<(nd + 3) / 4, 256, 0, stream>>>(xcur[dt], Dv + (size_t)idx0 * HID, ad_, nd);
        pass_a<8><<<(E + 255) / 256, 256, 0, stream>>>(ei[t], ei[t] + E, as_, ad_, ea[t],
                                                       w32 + (size_t)idx0 * 32, cv + idx0, E,
                                                       logits, mbuf);
        pass_b1<8><<<(E + 255) / 256, 256, 0, stream>>>(ei[t] + E, logits, mbuf, den, E);
        pass_b2<8><<<((size_t)E * 32 + 255) / 256, 256, 0, stream>>>(ei[t], ei[t] + E, logits,
                                                                     den, xs, agg[dt], E);
      } else {
        rowdot<1><<<(ns + 3) / 4, 256, 0, stream>>>(xcur[st], Sv + (size_t)idx0 * HID, as_, ns);
        rowdot<1><<<(nd + 3) / 4, 256, 0, stream>>>(xcur[dt], Dv + (size_t)idx0 * HID, ad_, nd);
        pass_a<1><<<(E + 255) / 256, 256, 0, stream>>>(ei[t], ei[t] + E, as_, ad_, ea[t],
                                                       w32 + (size_t)idx0 * 32, cv + idx0, E,
                                                       logits, mbuf);
        pass_b1<1><<<(E + 255) / 256, 256, 0, stream>>>(ei[t] + E, logits, mbuf, den, E);
        pass_b2<1><<<((size_t)E * 32 + 255) / 256, 256, 0, stream>>>(ei[t], ei[t] + E, logits,
                                                                     den, xs, agg[dt], E);
      }
    }
    hipMemsetAsync(stats, 0, 3 * 256 * 4, stream);
    for (int nt = 0; nt < 3; nt++) {
      int N = kNNode[nt];
      int gsz = N / 2; if (gsz > 768) gsz = 768; if (gsz < 1) gsz = 1;
      colstats<<<gsz, 256, 0, stream>>>(agg[nt], N, stats + nt * 256);
      bn_apply<<<(unsigned)(((size_t)N * 32 + 255) / 256), 256, 0, stream>>>(
          agg[nt], xcur[nt], xnxt[nt], stats + nt * 256, N,
          gamma + (size_t)(l * 3 + nt) * HID, beta + (size_t)(l * 3 + nt) * HID, (l < 2) ? 1 : 0);
    }
    for (int nt = 0; nt < 3; nt++) { float* tmp = xcur[nt]; xcur[nt] = xnxt[nt]; xnxt[nt] = tmp; }
  }
  dim3 g(HID / 64, (kNOp + 63) / 64);
  gemm_f32<<<g, 256, 0, stream>>>(xcur[0], Wo, bo, (float*)d_out, kNOp, HID, HID);
}

// Round 2
// 2071.686 us; speedup vs baseline: 2.6861x; 2.6861x over previous
//
#include <hip/hip_runtime.h>
#include <cstdint>

#define HID 128

static constexpr int kNOp = 50000, kNMa = 1000, kNJob = 5000;
static constexpr int kEsz[5]  = {150000, 100000, 150000, 100000, 100000};
static constexpr int kSrcT[5] = {0, 0, 1, 2, 0};
static constexpr int kDstT[5] = {0, 1, 0, 0, 2};
static constexpr int kNNode[3] = {kNOp, kNMa, kNJob};
static constexpr int kKin[3]   = {64, 32, 16};

// ---------------------------------------------------------------- GEMM (fp32)
__global__ __launch_bounds__(256) void gemm_f32(
    const float* __restrict__ A, const float* __restrict__ B,
    const float* __restrict__ bias, float* __restrict__ C,
    int M, int N, int K) {
  __shared__ float As[16][65];
  __shared__ float Bs[16][64];
  const int bm = blockIdx.y * 64, bn = blockIdx.x * 64;
  const int tid = threadIdx.x;
  const int tr = tid >> 4, tc = tid & 15;
  float acc[4][4] = {};
  for (int k0 = 0; k0 < K; k0 += 16) {
    {
      int r = tid >> 2, kk = (tid & 3) * 4;
      int row = bm + r;
      float4 v = make_float4(0.f, 0.f, 0.f, 0.f);
      if (row < M) v = *(const float4*)(A + (size_t)row * K + k0 + kk);
      As[kk + 0][r] = v.x; As[kk + 1][r] = v.y;
      As[kk + 2][r] = v.z; As[kk + 3][r] = v.w;
    }
    {
      int r = tid >> 4, c = (tid & 15) * 4;
      float4 v = *(const float4*)(B + (size_t)(k0 + r) * N + bn + c);
      *(float4*)&Bs[r][c] = v;
    }
    __syncthreads();
#pragma unroll
    for (int kk = 0; kk < 16; kk++) {
      float a[4], b[4];
#pragma unroll
      for (int i = 0; i < 4; i++) a[i] = As[kk][tr * 4 + i];
#pragma unroll
      for (int j = 0; j < 4; j++) b[j] = Bs[kk][tc * 4 + j];
#pragma unroll
      for (int i = 0; i < 4; i++)
#pragma unroll
        for (int j = 0; j < 4; j++) acc[i][j] += a[i] * b[j];
    }
    __syncthreads();
  }
#pragma unroll
  for (int i = 0; i < 4; i++) {
    int row = bm + tr * 4 + i;
    if (row >= M) continue;
    int col = bn + tc * 4;
    float4 v;
    v.x = acc[i][0]; v.y = acc[i][1]; v.z = acc[i][2]; v.w = acc[i][3];
    if (bias) { v.x += bias[col]; v.y += bias[col + 1]; v.z += bias[col + 2]; v.w += bias[col + 3]; }
    *(float4*)(C + (size_t)row * N + col) = v;
  }
}

// ------------------------------------------------- fold attention vectors
__global__ void fold_kernel(const float* __restrict__ Wg, const float* __restrict__ att_s,
                            const float* __restrict__ att_d, const float* __restrict__ Wge,
                            const float* __restrict__ att_e, const float* __restrict__ Wep,
                            const float* __restrict__ bep,
                            float* __restrict__ S, float* __restrict__ D,
                            float* __restrict__ w32, float* __restrict__ cvec) {
  int idx = blockIdx.x;          // (l*5+t)*8 + h
  int h = idx & 7, lt = idx >> 3;
  int l = lt / 5, t = lt % 5;
  int H = (l < 2) ? 8 : 1, C = HID / H;
  if (h >= H) return;
  int k = threadIdx.x;           // 0..127
  const float* wg  = Wg  + (size_t)lt * HID * HID;
  const float* wge = Wge + (size_t)lt * HID * HID;
  const float* as_ = att_s + (size_t)lt * HID + h * C;
  const float* ad_ = att_d + (size_t)lt * HID + h * C;
  const float* ae_ = att_e + (size_t)lt * HID + h * C;
  float s = 0.f, d = 0.f, v = 0.f;
  for (int c = 0; c < C; c++) {
    float wr = wg[(size_t)k * HID + h * C + c];
    s += wr * as_[c];
    d += wr * ad_[c];
    v += wge[(size_t)k * HID + h * C + c] * ae_[c];
  }
  S[(size_t)idx * HID + k] = s;
  D[(size_t)idx * HID + k] = d;
  __shared__ float vs[HID];
  vs[k] = v;
  __syncthreads();
  if (k < 32) {
    const float* wp = Wep + (size_t)t * 32 * HID + (size_t)k * HID;
    float a = 0.f;
    for (int j = 0; j < HID; j++) a += wp[j] * vs[j];
    w32[(size_t)idx * 32 + k] = a;
  }
  if (k == 32) {
    const float* bp = bep + (size_t)t * HID;
    float a = 0.f;
    for (int j = 0; j < HID; j++) a += bp[j] * vs[j];
    cvec[idx] = a;
  }
}

// -------------------------------------------- a_s/a_d: out[n,h] = x[n,:]·V[h,:]
template <int H>
__global__ void rowdot(const float* __restrict__ x, const float* __restrict__ V,
                       float* __restrict__ out, int N) {
  int lane = threadIdx.x & 63;
  int node = (int)((blockIdx.x * (size_t)blockDim.x + threadIdx.x) >> 6);
  if (node >= N) return;
  float2 xv = ((const float2*)(x + (size_t)node * HID))[lane];
  float acc[H];
#pragma unroll
  for (int h = 0; h < H; h++) {
    float2 vv = ((const float2*)(V + (size_t)h * HID))[lane];
    acc[h] = xv.x * vv.x + xv.y * vv.y;
  }
#pragma unroll
  for (int off = 32; off; off >>= 1)
#pragma unroll
    for (int h = 0; h < H; h++) acc[h] += __shfl_xor(acc[h], off, 64);
  if (lane == 0) {
#pragma unroll
    for (int h = 0; h < H; h++) out[(size_t)node * H + h] = acc[h];
  }
}

// ------------------------------------------------------------ CSR building
__global__ void hist_k(const int* __restrict__ dst, int* __restrict__ cnt, int E) {
  int e = blockIdx.x * blockDim.x + threadIdx.x;
  if (e < E) atomicAdd(&cnt[dst[e]], 1);
}

__global__ void scan_blocks(const int* __restrict__ in, int* __restrict__ out,
                            int* __restrict__ bsums, int n) {
  __shared__ int sh[256];
  int t = threadIdx.x;
  int base = blockIdx.x * 1024 + t * 4;
  int v[4]; int s = 0;
#pragma unroll
  for (int j = 0; j < 4; j++) { v[j] = (base + j < n) ? in[base + j] : 0; s += v[j]; }
  sh[t] = s;
  __syncthreads();
  for (int off = 1; off < 256; off <<= 1) {
    int x = (t >= off) ? sh[t - off] : 0;
    __syncthreads();
    sh[t] += x;
    __syncthreads();
  }
  int excl = sh[t] - s;
  int run = excl;
#pragma unroll
  for (int j = 0; j < 4; j++) { if (base + j < n) out[base + j] = run; run += v[j]; }
  if (t == 255) bsums[blockIdx.x] = sh[255];
}

__global__ void scan_carry(int* bsums, int nb) {
  if (threadIdx.x == 0 && blockIdx.x == 0) {
    int run = 0;
    for (int b = 0; b < nb; b++) { int x = bsums[b]; bsums[b] = run; run += x; }
  }
}

__global__ void scan_add(int* __restrict__ out, const int* __restrict__ bsums, int n) {
  int base = blockIdx.x * 1024 + threadIdx.x * 4;
  int c = bsums[blockIdx.x];
#pragma unroll
  for (int j = 0; j < 4; j++) if (base + j < n) out[base + j] += c;
}

__global__ void copy_k(const int* __restrict__ in, int* __restrict__ out, int n) {
  int i = blockIdx.x * blockDim.x + threadIdx.x;
  if (i < n) out[i] = in[i];
}

__global__ void scatter_k(const int* __restrict__ src, const int* __restrict__ dst,
                          int* __restrict__ cursor, int* __restrict__ perm,
                          int* __restrict__ ssrc, int E) {
  int e = blockIdx.x * blockDim.x + threadIdx.x;
  if (e >= E) return;
  int d = dst[e];
  int p = atomicAdd(&cursor[d], 1);
  perm[e] = p;
  ssrc[p] = src[e];
}

// ----------------------------- pass A: logits written in CSR-permuted order
template <int H>
__global__ void pass_a(const int* __restrict__ src, const int* __restrict__ dst,
                       const int* __restrict__ perm,
                       const float* __restrict__ a_s, const float* __restrict__ a_d,
                       const float* __restrict__ ea, const float* __restrict__ w32,
                       const float* __restrict__ cvec, int E,
                       float* __restrict__ logits) {
  __shared__ float w[H][32];
  __shared__ float cc[H];
  for (int i = threadIdx.x; i < H * 32; i += blockDim.x) {
    int h = i >> 5, k = i & 31;
    w[h][k] = w32[h * 32 + k];
  }
  if (threadIdx.x < H) cc[threadIdx.x] = cvec[threadIdx.x];
  __syncthreads();
  int e = blockIdx.x * blockDim.x + threadIdx.x;
  if (e >= E) return;
  int s = src[e], d = dst[e], pe = perm[e];
  float x[32];
  const float4* p = (const float4*)(ea + (size_t)e * 32);
#pragma unroll
  for (int i = 0; i < 8; i++) {
    float4 v = p[i];
    x[4 * i] = v.x; x[4 * i + 1] = v.y; x[4 * i + 2] = v.z; x[4 * i + 3] = v.w;
  }
#pragma unroll
  for (int h = 0; h < H; h++) {
    float a = cc[h];
#pragma unroll
    for (int k = 0; k < 32; k++) a += x[k] * w[h][k];
    float v = a + a_s[(size_t)s * H + h] + a_d[(size_t)d * H + h];
    v = v > 0.f ? v : 0.2f * v;
    logits[(size_t)pe * H + h] = v;
  }
}

// ---------------- fused softmax + weighted gather: one 64-lane wave per dst
template <int H>
__global__ void gat_gather(const int* __restrict__ rowstart, const int* __restrict__ ssrc,
                           const float* __restrict__ logits, const float* __restrict__ xs,
                           float* __restrict__ agg, int nd) {
  int node = (int)((blockIdx.x * (size_t)blockDim.x + threadIdx.x) >> 6);
  int lane = threadIdx.x & 63;
  if (node >= nd) return;
  int start = rowstart[node], end = rowstart[node + 1];
  int deg = end - start;
  if (deg == 0) return;
  const float* lg = logits + (size_t)start * H;
  int n = deg * H;
  // phase 1a: per-head max (lane handles head lane&7 when H==8; 64%8==0)
  float m = -3.0e38f;
  for (int idx = lane; idx < n; idx += 64) m = fmaxf(m, lg[idx]);
  if (H == 8) {
    m = fmaxf(m, __shfl_xor(m, 8));
    m = fmaxf(m, __shfl_xor(m, 16));
    m = fmaxf(m, __shfl_xor(m, 32));
  } else {
#pragma unroll
    for (int off = 1; off < 64; off <<= 1) m = fmaxf(m, __shfl_xor(m, off));
  }
  // phase 1b: per-head sum of exp
  float l = 0.f;
  for (int idx = lane; idx < n; idx += 64) l += expf(lg[idx] - m);
  if (H == 8) {
    l += __shfl_xor(l, 8);
    l += __shfl_xor(l, 16);
    l += __shfl_xor(l, 32);
  } else {
#pragma unroll
    for (int off = 1; off < 64; off <<= 1) l += __shfl_xor(l, off);
  }
  // per-lane head for the column chunk this lane owns (float2 -> cols 2*lane..2*lane+1)
  float m_mine = m, l_mine = l;
  int hm = 0;
  if (H == 8) {
    hm = lane >> 3;                 // C=16 cols/head, 8 lanes/head
    m_mine = __shfl(m, hm);         // lane h (h<8) holds head h stats
    l_mine = __shfl(l, hm);
  }
  // phase 2: weighted gather
  float2 acc = make_float2(0.f, 0.f);
  for (int i = 0; i < deg; i++) {
    int s = ssrc[start + i];
    float w = expf(lg[(size_t)i * H + hm] - m_mine);
    float2 xv = ((const float2*)(xs + (size_t)s * HID))[lane];
    acc.x += w * xv.x;
    acc.y += w * xv.y;
  }
  float inv = 1.f / (l_mine + 1e-16f);
  float2* ap = (float2*)(agg + (size_t)node * HID) + lane;
  float2 pv = *ap;
  pv.x += acc.x * inv;
  pv.y += acc.y * inv;
  *ap = pv;
}

// ------------------------------------------------- BatchNorm column stats
__global__ void colstats(const float* __restrict__ h, int N, float* __restrict__ stats) {
  int tid = threadIdx.x;
  int col = tid & 127, half = tid >> 7;
  float s = 0.f, q = 0.f;
  for (int r = blockIdx.x * 2 + half; r < N; r += gridDim.x * 2) {
    float v = h[(size_t)r * HID + col];
    s += v; q += v * v;
  }
  __shared__ float ls[256], lq[256];
  ls[tid] = s; lq[tid] = q;
  __syncthreads();
  if (tid < 128) {
    s = ls[tid] + ls[tid + 128];
    q = lq[tid] + lq[tid + 128];
    unsafeAtomicAdd(&stats[col], s);
    unsafeAtomicAdd(&stats[128 + col], q);
  }
}

// ------------------------------- BN apply + optional ReLU + residual
__global__ void bn_apply(const float* __restrict__ agg, const float* __restrict__ xold,
                         float* __restrict__ xnew, const float* __restrict__ stats, int N,
                         const float* __restrict__ gamma, const float* __restrict__ beta,
                         int relu) {
  size_t i = blockIdx.x * (size_t)blockDim.x + threadIdx.x;
  if (i >= (size_t)N * 32) return;
  int c4 = ((int)(i & 31)) * 4;
  float invN = 1.0f / (float)N;
  float4 av = ((const float4*)agg)[i];
  float4 xv = ((const float4*)xold)[i];
  float a[4] = {av.x, av.y, av.z, av.w};
  float xo[4] = {xv.x, xv.y, xv.z, xv.w};
  float o[4];
#pragma unroll
  for (int j = 0; j < 4; j++) {
    int c = c4 + j;
    float mu = stats[c] * invN;
    float var = stats[128 + c] * invN - mu * mu;
    float g = gamma[c] * rsqrtf(var + 1e-5f);
    float v = (a[j] - mu) * g + beta[c];
    if (relu) v = fmaxf(v, 0.f);
    o[j] = v + xo[j];
  }
  ((float4*)xnew)[i] = make_float4(o[0], o[1], o[2], o[3]);
}

// ============================================================== host driver
extern "C" void kernel_launch(void* const* d_in, const int* in_sizes, int n_in,
                              void* d_out, int out_size, void* d_ws, size_t ws_size,
                              hipStream_t stream) {
  const float* x_in[3] = {(const float*)d_in[0], (const float*)d_in[1], (const float*)d_in[2]};
  const int* ei[5];
  const float* ea[5];
  for (int t = 0; t < 5; t++) {
    ei[t] = (const int*)d_in[3 + 2 * t];
    ea[t] = (const float*)d_in[4 + 2 * t];
  }
  const float* Wn[3]  = {(const float*)d_in[13], (const float*)d_in[15], (const float*)d_in[17]};
  const float* bnb[3] = {(const float*)d_in[14], (const float*)d_in[16], (const float*)d_in[18]};
  const float* Wep   = (const float*)d_in[19];
  const float* bep   = (const float*)d_in[20];
  const float* Wg    = (const float*)d_in[21];
  const float* att_s = (const float*)d_in[22];
  const float* att_d = (const float*)d_in[23];
  const float* Wge   = (const float*)d_in[24];
  const float* att_e = (const float*)d_in[25];
  // d_in[26] = bg: cancelled exactly by BatchNorm mean-subtraction; unused.
  const float* gamma = (const float*)d_in[27];
  const float* beta  = (const float*)d_in[28];
  const float* Wo    = (const float*)d_in[29];
  const float* bo    = (const float*)d_in[30];

  float* ws = (float*)d_ws;
  size_t off = 0;
  auto alloc = [&](size_t n) { size_t o = off; off += (n + 255) & ~(size_t)255; return o; };

  float* xbuf[2][3];
  float* agg[3];
  for (int b = 0; b < 2; b++)
    for (int nt = 0; nt < 3; nt++) xbuf[b][nt] = ws + alloc((size_t)kNNode[nt] * HID);
  for (int nt = 0; nt < 3; nt++) agg[nt] = ws + alloc((size_t)kNNode[nt] * HID);
  float* xs      = ws + alloc((size_t)kNOp * HID);
  float* as_     = ws + alloc((size_t)kNOp * 8);
  float* ad_     = ws + alloc((size_t)kNOp * 8);
  float* logits  = ws + alloc((size_t)150000 * 8);
  float* Sv      = ws + alloc((size_t)3 * 5 * 8 * HID);
  float* Dv      = ws + alloc((size_t)3 * 5 * 8 * HID);
  float* w32     = ws + alloc((size_t)3 * 5 * 8 * 32);
  float* cv      = ws + alloc((size_t)3 * 5 * 8);
  float* stats   = ws + alloc((size_t)3 * 256);
  // CSR
  int* rs5[5]; int* perm5[5]; int* ssrc5[5];
  for (int t = 0; t < 5; t++) {
    rs5[t]   = (int*)(ws + alloc((size_t)kNNode[kDstT[t]] + 1));
    perm5[t] = (int*)(ws + alloc((size_t)kEsz[t]));
    ssrc5[t] = (int*)(ws + alloc((size_t)kEsz[t]));
  }
  int* cnt    = (int*)(ws + alloc(50008));
  int* cursor = (int*)(ws + alloc(50000));
  int* bsums  = (int*)(ws + alloc(64));
  (void)ws_size; (void)in_sizes; (void)n_in; (void)out_size;

  float *xcur[3], *xnxt[3];
  for (int nt = 0; nt < 3; nt++) { xcur[nt] = xbuf[0][nt]; xnxt[nt] = xbuf[1][nt]; }

  // -------- CSR build (indices identical across layers -> build once)
  for (int t = 0; t < 5; t++) {
    int E = kEsz[t], nd = kNNode[kDstT[t]];
    int n1 = nd + 1;
    hipMemsetAsync(cnt, 0, (size_t)n1 * 4, stream);
    hist_k<<<(E + 255) / 256, 256, 0, stream>>>(ei[t] + E, cnt, E);
    int nb = (n1 + 1023) / 1024;
    scan_blocks<<<nb, 256, 0, stream>>>(cnt, rs5[t], bsums, n1);
    scan_carry<<<1, 64, 0, stream>>>(bsums, nb);
    scan_add<<<nb, 256, 0, stream>>>(rs5[t], bsums, n1);
    copy_k<<<(nd + 255) / 256, 256, 0, stream>>>(rs5[t], cursor, nd);
    scatter_k<<<(E + 255) / 256, 256, 0, stream>>>(ei[t], ei[t] + E, cursor, perm5[t], ssrc5[t], E);
  }

  // -------- node input projections
  for (int nt = 0; nt < 3; nt++) {
    dim3 g(HID / 64, (kNNode[nt] + 63) / 64);
    gemm_f32<<<g, 256, 0, stream>>>(x_in[nt], Wn[nt], bnb[nt], xcur[nt], kNNode[nt], HID, kKin[nt]);
  }
  fold_kernel<<<120, 128, 0, stream>>>(Wg, att_s, att_d, Wge, att_e, Wep, bep, Sv, Dv, w32, cv);

  for (int l = 0; l < 3; l++) {
    int H = (l < 2) ? 8 : 1;
    for (int nt = 0; nt < 3; nt++)
      hipMemsetAsync(agg[nt], 0, (size_t)kNNode[nt] * HID * 4, stream);
    for (int t = 0; t < 5; t++) {
      int st = kSrcT[t], dt = kDstT[t], E = kEsz[t];
      int ns = kNNode[st], nd = kNNode[dt];
      int idx0 = (l * 5 + t) * 8;
      dim3 g(HID / 64, (ns + 63) / 64);
      gemm_f32<<<g, 256, 0, stream>>>(xcur[st], Wg + (size_t)(l * 5 + t) * HID * HID, nullptr,
                                      xs, ns, HID, HID);
      if (H == 8) {
        rowdot<8><<<(ns + 3) / 4, 256, 0, stream>>>(xcur[st], Sv + (size_t)idx0 * HID, as_, ns);
        rowdot<8><<<(nd + 3) / 4, 256, 0, stream>>>(xcur[dt], Dv + (size_t)idx0 * HID, ad_, nd);
        pass_a<8><<<(E + 255) / 256, 256, 0, stream>>>(ei[t], ei[t] + E, perm5[t], as_, ad_, ea[t],
                                                       w32 + (size_t)idx0 * 32, cv + idx0, E, logits);
        gat_gather<8><<<(nd + 3) / 4, 256, 0, stream>>>(rs5[t], ssrc5[t], logits, xs, agg[dt], nd);
      } else {
        rowdot<1><<<(ns + 3) / 4, 256, 0, stream>>>(xcur[st], Sv + (size_t)idx0 * HID, as_, ns);
        rowdot<1><<<(nd + 3) / 4, 256, 0, stream>>>(xcur[dt], Dv + (size_t)idx0 * HID, ad_, nd);
        pass_a<1><<<(E + 255) / 256, 256, 0, stream>>>(ei[t], ei[t] + E, perm5[t], as_, ad_, ea[t],
                                                       w32 + (size_t)idx0 * 32, cv + idx0, E, logits);
        gat_gather<1><<<(nd + 3) / 4, 256, 0, stream>>>(rs5[t], ssrc5[t], logits, xs, agg[dt], nd);
      }
    }
    hipMemsetAsync(stats, 0, 3 * 256 * 4, stream);
    for (int nt = 0; nt < 3; nt++) {
      int N = kNNode[nt];
      int gsz = N / 2; if (gsz > 768) gsz = 768; if (gsz < 1) gsz = 1;
      colstats<<<gsz, 256, 0, stream>>>(agg[nt], N, stats + nt * 256);
      bn_apply<<<(unsigned)(((size_t)N * 32 + 255) / 256), 256, 0, stream>>>(
          agg[nt], xcur[nt], xnxt[nt], stats + nt * 256, N,
          gamma + (size_t)(l * 3 + nt) * HID, beta + (size_t)(l * 3 + nt) * HID, (l < 2) ? 1 : 0);
    }
    for (int nt = 0; nt < 3; nt++) { float* tmp = xcur[nt]; xcur[nt] = xnxt[nt]; xnxt[nt] = tmp; }
  }
  dim3 g(HID / 64, (kNOp + 63) / 64);
  gemm_f32<<<g, 256, 0, stream>>>(xcur[0], Wo, bo, (float*)d_out, kNOp, HID, HID);
}

// Round 3
// 1785.971 us; speedup vs baseline: 3.1159x; 1.1600x over previous
//
#include <hip/hip_runtime.h>
#include <cstdint>

#define HID 128

static constexpr int kNOp = 50000, kNMa = 1000, kNJob = 5000;
static constexpr int kEsz[5]  = {150000, 100000, 150000, 100000, 100000};
static constexpr int kSrcT[5] = {0, 0, 1, 2, 0};
static constexpr int kDstT[5] = {0, 1, 0, 0, 2};
static constexpr int kNNode[3] = {kNOp, kNMa, kNJob};

typedef __attribute__((ext_vector_type(8))) __bf16 bf16x8;
typedef __attribute__((ext_vector_type(4))) float f32x4;

__device__ inline unsigned short f2b(float f) {
  unsigned u = __float_as_uint(f);
  unsigned r = (u + 0x7FFFu + ((u >> 16) & 1u)) >> 16;
  return (unsigned short)r;
}
__device__ inline float b2f(unsigned short u) {
  return __uint_as_float(((unsigned)u) << 16);
}

// ------------------------------------------------ fp32 -> bf16 (pad K to Kp)
__global__ void conv_pad(const float* __restrict__ in, unsigned short* __restrict__ out,
                         int M, int K, int Kp) {
  int i = blockIdx.x * blockDim.x + threadIdx.x;
  if (i >= M * Kp) return;
  int r = i / Kp, c = i - r * Kp;
  out[i] = (c < K) ? f2b(in[(size_t)r * K + c]) : (unsigned short)0;
}

// ---------------------- W[K x N] fp32 -> Wt[N x Kp] bf16 (batched, zero-pad K)
__global__ void transpose_w(const float* __restrict__ W, unsigned short* __restrict__ Wt,
                            int K, int N, int Kp, int nmat) {
  int i = blockIdx.x * blockDim.x + threadIdx.x;
  int per = N * Kp;
  if (i >= nmat * per) return;
  int b = i / per, rem = i - b * per;
  int n = rem / Kp, k = rem - n * Kp;
  Wt[i] = (k < K) ? f2b(W[(size_t)b * K * N + (size_t)k * N + n]) : (unsigned short)0;
}

// --------------------------------------------------------- bf16 MFMA GEMM
// C[M x 128] = A[M x K]bf16 @ B (given as Bt[128 x K] bf16) (+bias).
// One wave per 16-row strip; fp32 and/or bf16 outputs.
template <int KC>   // K = KC*32
__global__ __launch_bounds__(256) void gemm_mfma(
    const unsigned short* __restrict__ A, const unsigned short* __restrict__ Bt,
    const float* __restrict__ bias, float* __restrict__ Cf,
    unsigned short* __restrict__ Cb, int M) {
  const int K = KC * 32;
  int w = blockIdx.x * 4 + (threadIdx.x >> 6);
  int m0 = w * 16;
  if (m0 >= M) return;
  int lane = threadIdx.x & 63;
  int l16 = lane & 15, quad = lane >> 4;
  int arow = m0 + l16; if (arow >= M) arow = M - 1;
  bf16x8 af[KC];
#pragma unroll
  for (int kc = 0; kc < KC; kc++) {
    int4 raw = *(const int4*)(A + (size_t)arow * K + kc * 32 + quad * 8);
    af[kc] = __builtin_bit_cast(bf16x8, raw);
  }
#pragma unroll
  for (int nt = 0; nt < 8; nt++) {
    int col = nt * 16 + l16;
    f32x4 acc = {0.f, 0.f, 0.f, 0.f};
#pragma unroll
    for (int kc = 0; kc < KC; kc++) {
      int4 braw = *(const int4*)(Bt + (size_t)col * K + kc * 32 + quad * 8);
      acc = __builtin_amdgcn_mfma_f32_16x16x32_bf16(
          af[kc], __builtin_bit_cast(bf16x8, braw), acc, 0, 0, 0);
    }
    float bv = bias ? bias[col] : 0.f;
#pragma unroll
    for (int r = 0; r < 4; r++) {
      int row = m0 + quad * 4 + r;
      if (row < M) {
        float v = acc[r] + bv;
        if (Cf) Cf[(size_t)row * HID + col] = v;
        if (Cb) Cb[(size_t)row * HID + col] = f2b(v);
      }
    }
  }
}

// ------------------------------------------------- fold attention vectors
__global__ void fold_kernel(const float* __restrict__ Wg, const float* __restrict__ att_s,
                            const float* __restrict__ att_d, const float* __restrict__ Wge,
                            const float* __restrict__ att_e, const float* __restrict__ Wep,
                            const float* __restrict__ bep,
                            float* __restrict__ S, float* __restrict__ D,
                            float* __restrict__ w32, float* __restrict__ cvec) {
  int idx = blockIdx.x;          // (l*5+t)*8 + h
  int h = idx & 7, lt = idx >> 3;
  int l = lt / 5;
  int H = (l < 2) ? 8 : 1, C = HID / H;
  if (h >= H) return;
  int k = threadIdx.x;           // 0..127
  int t = lt % 5;
  const float* wg  = Wg  + (size_t)lt * HID * HID;
  const float* wge = Wge + (size_t)lt * HID * HID;
  const float* as_ = att_s + (size_t)lt * HID + h * C;
  const float* ad_ = att_d + (size_t)lt * HID + h * C;
  const float* ae_ = att_e + (size_t)lt * HID + h * C;
  float s = 0.f, d = 0.f, v = 0.f;
  for (int c = 0; c < C; c++) {
    float wr = wg[(size_t)k * HID + h * C + c];
    s += wr * as_[c];
    d += wr * ad_[c];
    v += wge[(size_t)k * HID + h * C + c] * ae_[c];
  }
  S[(size_t)idx * HID + k] = s;
  D[(size_t)idx * HID + k] = d;
  __shared__ float vs[HID];
  vs[k] = v;
  __syncthreads();
  if (k < 32) {
    const float* wp = Wep + (size_t)t * 32 * HID + (size_t)k * HID;
    float a = 0.f;
    for (int j = 0; j < HID; j++) a += wp[j] * vs[j];
    w32[(size_t)idx * 32 + k] = a;
  }
  if (k == 32) {
    const float* bp = bep + (size_t)t * HID;
    float a = 0.f;
    for (int j = 0; j < HID; j++) a += bp[j] * vs[j];
    cvec[idx] = a;
  }
}

// -------------------------------------------- a_s/a_d: out[n,h] = x[n,:]·V[h,:]
template <int H>
__global__ void rowdot(const float* __restrict__ x, const float* __restrict__ V,
                       float* __restrict__ out, int N) {
  int lane = threadIdx.x & 63;
  int node = (int)((blockIdx.x * (size_t)blockDim.x + threadIdx.x) >> 6);
  if (node >= N) return;
  float2 xv = ((const float2*)(x + (size_t)node * HID))[lane];
  float acc[H];
#pragma unroll
  for (int h = 0; h < H; h++) {
    float2 vv = ((const float2*)(V + (size_t)h * HID))[lane];
    acc[h] = xv.x * vv.x + xv.y * vv.y;
  }
#pragma unroll
  for (int off = 32; off; off >>= 1)
#pragma unroll
    for (int h = 0; h < H; h++) acc[h] += __shfl_xor(acc[h], off, 64);
  if (lane == 0) {
#pragma unroll
    for (int h = 0; h < H; h++) out[(size_t)node * H + h] = acc[h];
  }
}

// ------------------------------------------------------------ CSR building
__global__ void hist_k(const int* __restrict__ dst, int* __restrict__ cnt, int E) {
  int e = blockIdx.x * blockDim.x + threadIdx.x;
  if (e < E) atomicAdd(&cnt[dst[e]], 1);
}

__global__ void scan_blocks(const int* __restrict__ in, int* __restrict__ out,
                            int* __restrict__ bsums, int n) {
  __shared__ int sh[256];
  int t = threadIdx.x;
  int base = blockIdx.x * 1024 + t * 4;
  int v[4]; int s = 0;
#pragma unroll
  for (int j = 0; j < 4; j++) { v[j] = (base + j < n) ? in[base + j] : 0; s += v[j]; }
  sh[t] = s;
  __syncthreads();
  for (int off = 1; off < 256; off <<= 1) {
    int x = (t >= off) ? sh[t - off] : 0;
    __syncthreads();
    sh[t] += x;
    __syncthreads();
  }
  int excl = sh[t] - s;
  int run = excl;
#pragma unroll
  for (int j = 0; j < 4; j++) { if (base + j < n) out[base + j] = run; run += v[j]; }
  if (t == 255) bsums[blockIdx.x] = sh[255];
}

__global__ void scan_carry(int* bsums, int nb) {
  if (threadIdx.x == 0 && blockIdx.x == 0) {
    int run = 0;
    for (int b = 0; b < nb; b++) { int x = bsums[b]; bsums[b] = run; run += x; }
  }
}

__global__ void scan_add(int* __restrict__ out, const int* __restrict__ bsums, int n) {
  int base = blockIdx.x * 1024 + threadIdx.x * 4;
  int c = bsums[blockIdx.x];
#pragma unroll
  for (int j = 0; j < 4; j++) if (base + j < n) out[base + j] += c;
}

__global__ void copy_k(const int* __restrict__ in, int* __restrict__ out, int n) {
  int i = blockIdx.x * blockDim.x + threadIdx.x;
  if (i < n) out[i] = in[i];
}

__global__ void scatter_k(const int* __restrict__ src, const int* __restrict__ dst,
                          int* __restrict__ cursor, int* __restrict__ perm,
                          int* __restrict__ ssrc, int E) {
  int e = blockIdx.x * blockDim.x + threadIdx.x;
  if (e >= E) return;
  int d = dst[e];
  int p = atomicAdd(&cursor[d], 1);
  perm[e] = p;
  ssrc[p] = src[e];
}

// ----------------------------- pass A: logits written in CSR-permuted order
template <int H>
__global__ void pass_a(const int* __restrict__ src, const int* __restrict__ dst,
                       const int* __restrict__ perm,
                       const float* __restrict__ a_s, const float* __restrict__ a_d,
                       const float* __restrict__ ea, const float* __restrict__ w32,
                       const float* __restrict__ cvec, int E,
                       float* __restrict__ logits) {
  __shared__ float w[H][32];
  __shared__ float cc[H];
  for (int i = threadIdx.x; i < H * 32; i += blockDim.x) {
    int h = i >> 5, k = i & 31;
    w[h][k] = w32[h * 32 + k];
  }
  if (threadIdx.x < H) cc[threadIdx.x] = cvec[threadIdx.x];
  __syncthreads();
  int e = blockIdx.x * blockDim.x + threadIdx.x;
  if (e >= E) return;
  int s = src[e], d = dst[e], pe = perm[e];
  float x[32];
  const float4* p = (const float4*)(ea + (size_t)e * 32);
#pragma unroll
  for (int i = 0; i < 8; i++) {
    float4 v = p[i];
    x[4 * i] = v.x; x[4 * i + 1] = v.y; x[4 * i + 2] = v.z; x[4 * i + 3] = v.w;
  }
#pragma unroll
  for (int h = 0; h < H; h++) {
    float a = cc[h];
#pragma unroll
    for (int k = 0; k < 32; k++) a += x[k] * w[h][k];
    float v = a + a_s[(size_t)s * H + h] + a_d[(size_t)d * H + h];
    v = v > 0.f ? v : 0.2f * v;
    logits[(size_t)pe * H + h] = v;
  }
}

// -------------- per-relation softmax+gather accumulation (register-resident)
// 4 edges in flight (16 lanes x 16B bf16 each); ssrc prefetched 64 at a time.
template <int H>
__device__ inline void gather_one(const int* __restrict__ rs, const int* __restrict__ ssrc,
                                  const float* __restrict__ lg, const unsigned short* __restrict__ xs,
                                  int node, int lane, float* acc) {
  int start = rs[node], end = rs[node + 1];
  int deg = end - start;
  if (deg == 0) return;
  const float* L = lg + (size_t)start * H;
  int n = deg * H;
  float m = -3.0e38f;
  for (int idx = lane; idx < n; idx += 64) m = fmaxf(m, L[idx]);
  if (H == 8) {
    m = fmaxf(m, __shfl_xor(m, 8));
    m = fmaxf(m, __shfl_xor(m, 16));
    m = fmaxf(m, __shfl_xor(m, 32));
  } else {
#pragma unroll
    for (int off = 1; off < 64; off <<= 1) m = fmaxf(m, __shfl_xor(m, off));
  }
  float l = 0.f;
  for (int idx = lane; idx < n; idx += 64) l += expf(L[idx] - m);
  if (H == 8) {
    l += __shfl_xor(l, 8);
    l += __shfl_xor(l, 16);
    l += __shfl_xor(l, 32);
  } else {
#pragma unroll
    for (int off = 1; off < 64; off <<= 1) l += __shfl_xor(l, off);
  }
  int l16 = lane & 15, quad = lane >> 4;
  int h = (H == 8) ? (l16 >> 1) : 0;          // lane covers cols 8*l16..+7 (head = c/16)
  float mh = (H == 8) ? __shfl(m, h) : m;
  float lh = (H == 8) ? __shfl(l, h) : l;
  float inv = 1.f / (lh + 1e-16f);
  float sub[8] = {0.f, 0.f, 0.f, 0.f, 0.f, 0.f, 0.f, 0.f};
  for (int base = 0; base < deg; base += 64) {
    int nchunk = deg - base; if (nchunk > 64) nchunk = 64;
    int sv = (lane < nchunk) ? ssrc[start + base + lane] : 0;
    for (int i = 0; i < nchunk; i += 4) {
      int e = i + quad;
      bool act = e < nchunk;
      int s = __shfl(sv, act ? e : 0);
      float wgt = act ? expf(L[(size_t)(base + e) * H + h] - mh) : 0.f;
      if (act) {
        int4 raw = *(const int4*)(xs + (size_t)s * HID + l16 * 8);
        union { int4 v; unsigned short us[8]; } u; u.v = raw;
#pragma unroll
        for (int j = 0; j < 8; j++) sub[j] += wgt * b2f(u.us[j]);
      }
    }
  }
#pragma unroll
  for (int j = 0; j < 8; j++) acc[j] += inv * sub[j];
}

struct GArgs { const int* rs; const int* ssrc; const float* lg; const unsigned short* xs; };

template <int H, int R>
__global__ void gat_gather(GArgs g0, GArgs g1, GArgs g2, float* __restrict__ agg, int nd) {
  int node = (int)((blockIdx.x * (size_t)blockDim.x + threadIdx.x) >> 6);
  int lane = threadIdx.x & 63;
  if (node >= nd) return;
  float acc[8] = {0.f, 0.f, 0.f, 0.f, 0.f, 0.f, 0.f, 0.f};
  gather_one<H>(g0.rs, g0.ssrc, g0.lg, g0.xs, node, lane, acc);
  if (R > 1) gather_one<H>(g1.rs, g1.ssrc, g1.lg, g1.xs, node, lane, acc);
  if (R > 2) gather_one<H>(g2.rs, g2.ssrc, g2.lg, g2.xs, node, lane, acc);
#pragma unroll
  for (int j = 0; j < 8; j++) {
    acc[j] += __shfl_xor(acc[j], 16);
    acc[j] += __shfl_xor(acc[j], 32);
  }
  if ((lane >> 4) == 0) {
    float* p = agg + (size_t)node * HID + lane * 8;
    *(float4*)p = make_float4(acc[0], acc[1], acc[2], acc[3]);
    *(float4*)(p + 4) = make_float4(acc[4], acc[5], acc[6], acc[7]);
  }
}

// ------------------------------------------------- BatchNorm column stats
__global__ void colstats(const float* __restrict__ h, int N, float* __restrict__ stats) {
  int tid = threadIdx.x;
  int col = tid & 127, half = tid >> 7;
  float s = 0.f, q = 0.f;
  for (int r = blockIdx.x * 2 + half; r < N; r += gridDim.x * 2) {
    float v = h[(size_t)r * HID + col];
    s += v; q += v * v;
  }
  __shared__ float ls[256], lq[256];
  ls[tid] = s; lq[tid] = q;
  __syncthreads();
  if (tid < 128) {
    s = ls[tid] + ls[tid + 128];
    q = lq[tid] + lq[tid + 128];
    unsafeAtomicAdd(&stats[col], s);
    unsafeAtomicAdd(&stats[128 + col], q);
  }
}

// --------------------- BN apply + optional ReLU + residual; fp32 + bf16 out
__global__ void bn_apply(const float* __restrict__ agg, const float* __restrict__ xold,
                         float* __restrict__ xnew, unsigned short* __restrict__ xnb,
                         const float* __restrict__ stats, int N,
                         const float* __restrict__ gamma, const float* __restrict__ beta,
                         int relu) {
  size_t i = blockIdx.x * (size_t)blockDim.x + threadIdx.x;
  if (i >= (size_t)N * 32) return;
  int c4 = ((int)(i & 31)) * 4;
  float invN = 1.0f / (float)N;
  float4 av = ((const float4*)agg)[i];
  float4 xv = ((const float4*)xold)[i];
  float a[4] = {av.x, av.y, av.z, av.w};
  float xo[4] = {xv.x, xv.y, xv.z, xv.w};
  float o[4];
#pragma unroll
  for (int j = 0; j < 4; j++) {
    int c = c4 + j;
    float mu = stats[c] * invN;
    float var = stats[128 + c] * invN - mu * mu;
    float g = gamma[c] * rsqrtf(var + 1e-5f);
    float v = (a[j] - mu) * g + beta[c];
    if (relu) v = fmaxf(v, 0.f);
    o[j] = v + xo[j];
  }
  ((float4*)xnew)[i] = make_float4(o[0], o[1], o[2], o[3]);
  ((ushort4*)xnb)[i] = make_ushort4(f2b(o[0]), f2b(o[1]), f2b(o[2]), f2b(o[3]));
}

// ============================================================== host driver
extern "C" void kernel_launch(void* const* d_in, const int* in_sizes, int n_in,
                              void* d_out, int out_size, void* d_ws, size_t ws_size,
                              hipStream_t stream) {
  const float* x_in[3] = {(const float*)d_in[0], (const float*)d_in[1], (const float*)d_in[2]};
  const int* ei[5];
  const float* ea[5];
  for (int t = 0; t < 5; t++) {
    ei[t] = (const int*)d_in[3 + 2 * t];
    ea[t] = (const float*)d_in[4 + 2 * t];
  }
  const float* Wn[3]  = {(const float*)d_in[13], (const float*)d_in[15], (const float*)d_in[17]};
  const float* bnb[3] = {(const float*)d_in[14], (const float*)d_in[16], (const float*)d_in[18]};
  const float* Wep   = (const float*)d_in[19];
  const float* bep   = (const float*)d_in[20];
  const float* Wg    = (const float*)d_in[21];
  const float* att_s = (const float*)d_in[22];
  const float* att_d = (const float*)d_in[23];
  const float* Wge   = (const float*)d_in[24];
  const float* att_e = (const float*)d_in[25];
  // d_in[26] = bg: cancelled exactly by BatchNorm mean-subtraction; unused.
  const float* gamma = (const float*)d_in[27];
  const float* beta  = (const float*)d_in[28];
  const float* Wo    = (const float*)d_in[29];
  const float* bo    = (const float*)d_in[30];

  float* ws = (float*)d_ws;
  size_t off = 0;
  auto alloc = [&](size_t nfloats) { size_t o = off; off += (nfloats + 255) & ~(size_t)255; return o; };
  auto allocb = [&](size_t nush) { return alloc((nush + 1) / 2); };  // bf16 in float words

  float* xbuf[2][3];
  float* agg[3];
  for (int b = 0; b < 2; b++)
    for (int nt = 0; nt < 3; nt++) xbuf[b][nt] = ws + alloc((size_t)kNNode[nt] * HID);
  for (int nt = 0; nt < 3; nt++) agg[nt] = ws + alloc((size_t)kNNode[nt] * HID);
  unsigned short* xcurb[3];
  for (int nt = 0; nt < 3; nt++) xcurb[nt] = (unsigned short*)(ws + allocb((size_t)kNNode[nt] * HID));
  unsigned short* xsb_op  = (unsigned short*)(ws + allocb((size_t)kNOp * HID));
  unsigned short* xsb_ma  = (unsigned short*)(ws + allocb((size_t)kNMa * HID));
  unsigned short* xsb_job = (unsigned short*)(ws + allocb((size_t)kNJob * HID));
  unsigned short* xinb_op  = (unsigned short*)(ws + allocb((size_t)kNOp * 64));
  unsigned short* xinb_ma  = (unsigned short*)(ws + allocb((size_t)kNMa * 32));
  unsigned short* xinb_job = (unsigned short*)(ws + allocb((size_t)kNJob * 32));
  unsigned short* WgT  = (unsigned short*)(ws + allocb((size_t)15 * HID * HID));
  unsigned short* WoT  = (unsigned short*)(ws + allocb((size_t)HID * HID));
  unsigned short* WnT_op  = (unsigned short*)(ws + allocb((size_t)HID * 64));
  unsigned short* WnT_ma  = (unsigned short*)(ws + allocb((size_t)HID * 32));
  unsigned short* WnT_job = (unsigned short*)(ws + allocb((size_t)HID * 32));
  float* as_     = ws + alloc((size_t)kNOp * 8);
  float* ad_     = ws + alloc((size_t)kNOp * 8);
  float* lg0     = ws + alloc((size_t)150000 * 8);   // also reused for t1/t4
  float* lg2     = ws + alloc((size_t)150000 * 8);
  float* lg3     = ws + alloc((size_t)100000 * 8);
  float* Sv      = ws + alloc((size_t)3 * 5 * 8 * HID);
  float* Dv      = ws + alloc((size_t)3 * 5 * 8 * HID);
  float* w32     = ws + alloc((size_t)3 * 5 * 8 * 32);
  float* cv      = ws + alloc((size_t)3 * 5 * 8);
  float* stats   = ws + alloc((size_t)3 * 256);
  int* rs5[5]; int* perm5[5]; int* ssrc5[5];
  for (int t = 0; t < 5; t++) {
    rs5[t]   = (int*)(ws + alloc((size_t)kNNode[kDstT[t]] + 1));
    perm5[t] = (int*)(ws + alloc((size_t)kEsz[t]));
    ssrc5[t] = (int*)(ws + alloc((size_t)kEsz[t]));
  }
  int* cnt    = (int*)(ws + alloc(50008));
  int* cursor = (int*)(ws + alloc(50000));
  int* bsums  = (int*)(ws + alloc(64));
  (void)ws_size; (void)in_sizes; (void)n_in; (void)out_size;

  float *xcur[3], *xnxt[3];
  for (int nt = 0; nt < 3; nt++) { xcur[nt] = xbuf[0][nt]; xnxt[nt] = xbuf[1][nt]; }

  // -------- CSR build (indices identical across layers -> build once)
  for (int t = 0; t < 5; t++) {
    int E = kEsz[t], nd = kNNode[kDstT[t]];
    int n1 = nd + 1;
    hipMemsetAsync(cnt, 0, (size_t)n1 * 4, stream);
    hist_k<<<(E + 255) / 256, 256, 0, stream>>>(ei[t] + E, cnt, E);
    int nb = (n1 + 1023) / 1024;
    scan_blocks<<<nb, 256, 0, stream>>>(cnt, rs5[t], bsums, n1);
    scan_carry<<<1, 64, 0, stream>>>(bsums, nb);
    scan_add<<<nb, 256, 0, stream>>>(rs5[t], bsums, n1);
    copy_k<<<(nd + 255) / 256, 256, 0, stream>>>(rs5[t], cursor, nd);
    scatter_k<<<(E + 255) / 256, 256, 0, stream>>>(ei[t], ei[t] + E, cursor, perm5[t], ssrc5[t], E);
  }

  // -------- weight/input bf16 conversions
  conv_pad<<<(kNOp * 64 + 255) / 256, 256, 0, stream>>>(x_in[0], xinb_op, kNOp, 64, 64);
  conv_pad<<<(kNMa * 32 + 255) / 256, 256, 0, stream>>>(x_in[1], xinb_ma, kNMa, 32, 32);
  conv_pad<<<(kNJob * 32 + 255) / 256, 256, 0, stream>>>(x_in[2], xinb_job, kNJob, 16, 32);
  transpose_w<<<(HID * 64 + 255) / 256, 256, 0, stream>>>(Wn[0], WnT_op, 64, HID, 64, 1);
  transpose_w<<<(HID * 32 + 255) / 256, 256, 0, stream>>>(Wn[1], WnT_ma, 32, HID, 32, 1);
  transpose_w<<<(HID * 32 + 255) / 256, 256, 0, stream>>>(Wn[2], WnT_job, 16, HID, 32, 1);
  transpose_w<<<(15 * HID * HID + 255) / 256, 256, 0, stream>>>(Wg, WgT, HID, HID, HID, 15);
  transpose_w<<<(HID * HID + 255) / 256, 256, 0, stream>>>(Wo, WoT, HID, HID, HID, 1);

  auto mgemm = [&](const unsigned short* A, const unsigned short* Bt, const float* bias,
                   float* Cf, unsigned short* Cb, int M, int K) {
    int blocks = ((M + 15) / 16 + 3) / 4;
    if (K == 128)     gemm_mfma<4><<<blocks, 256, 0, stream>>>(A, Bt, bias, Cf, Cb, M);
    else if (K == 64) gemm_mfma<2><<<blocks, 256, 0, stream>>>(A, Bt, bias, Cf, Cb, M);
    else              gemm_mfma<1><<<blocks, 256, 0, stream>>>(A, Bt, bias, Cf, Cb, M);
  };

  // -------- node input projections (fp32 + bf16 shadow)
  mgemm(xinb_op,  WnT_op,  bnb[0], xcur[0], xcurb[0], kNOp, 64);
  mgemm(xinb_ma,  WnT_ma,  bnb[1], xcur[1], xcurb[1], kNMa, 32);
  mgemm(xinb_job, WnT_job, bnb[2], xcur[2], xcurb[2], kNJob, 32);
  fold_kernel<<<120, 128, 0, stream>>>(Wg, att_s, att_d, Wge, att_e, Wep, bep, Sv, Dv, w32, cv);

  unsigned short* xsb_of[3] = {xsb_op, xsb_ma, xsb_job};  // indexed by src type

  for (int l = 0; l < 3; l++) {
    int H = (l < 2) ? 8 : 1;
    float* lgt[5] = {lg0, lg0, lg2, lg3, lg0};  // t1/t4 reuse lg0 (after fused gather)

    auto do_rel = [&](int t) {
      int st = kSrcT[t], dt = kDstT[t], E = kEsz[t];
      int ns = kNNode[st], nd = kNNode[dt];
      int idx0 = (l * 5 + t) * 8;
      mgemm(xcurb[st], WgT + (size_t)(l * 5 + t) * HID * HID, nullptr,
            nullptr, xsb_of[st], ns, 128);
      if (H == 8) {
        rowdot<8><<<(ns + 3) / 4, 256, 0, stream>>>(xcur[st], Sv + (size_t)idx0 * HID, as_, ns);
        rowdot<8><<<(nd + 3) / 4, 256, 0, stream>>>(xcur[dt], Dv + (size_t)idx0 * HID, ad_, nd);
        pass_a<8><<<(E + 255) / 256, 256, 0, stream>>>(ei[t], ei[t] + E, perm5[t], as_, ad_, ea[t],
                                                       w32 + (size_t)idx0 * 32, cv + idx0, E, lgt[t]);
      } else {
        rowdot<1><<<(ns + 3) / 4, 256, 0, stream>>>(xcur[st], Sv + (size_t)idx0 * HID, as_, ns);
        rowdot<1><<<(nd + 3) / 4, 256, 0, stream>>>(xcur[dt], Dv + (size_t)idx0 * HID, ad_, nd);
        pass_a<1><<<(E + 255) / 256, 256, 0, stream>>>(ei[t], ei[t] + E, perm5[t], as_, ad_, ea[t],
                                                       w32 + (size_t)idx0 * 32, cv + idx0, E, lgt[t]);
      }
    };

    // dst = operation: t0 (src op), t2 (src ma), t3 (src job) -> fused gather
    do_rel(0); do_rel(2); do_rel(3);
    GArgs g0 = {rs5[0], ssrc5[0], lg0, xsb_op};
    GArgs g2 = {rs5[2], ssrc5[2], lg2, xsb_ma};
    GArgs g3 = {rs5[3], ssrc5[3], lg3, xsb_job};
    if (H == 8)
      gat_gather<8, 3><<<(kNOp + 3) / 4, 256, 0, stream>>>(g0, g2, g3, agg[0], kNOp);
    else
      gat_gather<1, 3><<<(kNOp + 3) / 4, 256, 0, stream>>>(g0, g2, g3, agg[0], kNOp);
    // dst = machine: t1 (src op)
    do_rel(1);
    GArgs g1 = {rs5[1], ssrc5[1], lg0, xsb_op};
    if (H == 8)
      gat_gather<8, 1><<<(kNMa + 3) / 4, 256, 0, stream>>>(g1, g1, g1, agg[1], kNMa);
    else
      gat_gather<1, 1><<<(kNMa + 3) / 4, 256, 0, stream>>>(g1, g1, g1, agg[1], kNMa);
    // dst = job: t4 (src op)
    do_rel(4);
    GArgs g4 = {rs5[4], ssrc5[4], lg0, xsb_op};
    if (H == 8)
      gat_gather<8, 1><<<(kNJob + 3) / 4, 256, 0, stream>>>(g4, g4, g4, agg[2], kNJob);
    else
      gat_gather<1, 1><<<(kNJob + 3) / 4, 256, 0, stream>>>(g4, g4, g4, agg[2], kNJob);

    hipMemsetAsync(stats, 0, 3 * 256 * 4, stream);
    for (int nt = 0; nt < 3; nt++) {
      int N = kNNode[nt];
      int gsz = N / 2; if (gsz > 768) gsz = 768; if (gsz < 1) gsz = 1;
      colstats<<<gsz, 256, 0, stream>>>(agg[nt], N, stats + nt * 256);
      bn_apply<<<(unsigned)(((size_t)N * 32 + 255) / 256), 256, 0, stream>>>(
          agg[nt], xcur[nt], xnxt[nt], xcurb[nt], stats + nt * 256, N,
          gamma + (size_t)(l * 3 + nt) * HID, beta + (size_t)(l * 3 + nt) * HID, (l < 2) ? 1 : 0);
    }
    for (int nt = 0; nt < 3; nt++) { float* tmp = xcur[nt]; xcur[nt] = xnxt[nt]; xnxt[nt] = tmp; }
  }
  mgemm(xcurb[0], WoT, bo, (float*)d_out, nullptr, kNOp, 128);
}

// Round 7
// 1381.942 us; speedup vs baseline: 4.0268x; 1.2924x over previous
//
#include <hip/hip_runtime.h>
#include <cstdint>

#define HID 128

static constexpr int kNOp = 50000, kNMa = 1000, kNJob = 5000;
static constexpr int kNTot = 56000;                 // op | ma | job global node space
static constexpr int kETot = 600000;
static constexpr int kSeg = 156000;                 // (dst,relation) sub-segments
static constexpr int kEsz[5]   = {150000, 100000, 150000, 100000, 100000};
static constexpr int kSrcT[5]  = {0, 0, 1, 2, 0};
static constexpr int kNodeOff[3] = {0, 50000, 51000};
static constexpr int kEoff[6]  = {0, 150000, 250000, 400000, 500000, 600000};
static constexpr int kRoff[5]  = {0, 50000, 100000, 101000, 106000};  // xs_all/a_s row offset (src counts)
static constexpr int kRTot = 156000;
// a_d row offsets use DST counts: t0=op(50000), t1=ma(1000), t2=op(50000), t3=op(50000), t4=job(5000)
static constexpr int kAdoff[5] = {0, 50000, 51000, 101000, 151000};
static constexpr int kAdTot = 156000;

typedef __attribute__((ext_vector_type(8))) __bf16 bf16x8;
typedef __attribute__((ext_vector_type(4))) float f32x4;

__device__ inline unsigned short f2b(float f) {
  unsigned u = __float_as_uint(f);
  unsigned r = (u + 0x7FFFu + ((u >> 16) & 1u)) >> 16;
  return (unsigned short)r;
}
__device__ inline float b2f(unsigned short u) {
  return __uint_as_float(((unsigned)u) << 16);
}

// (dst,relation) -> softmax sub-segment id; op sub-segments contiguous per node
__device__ inline int seg_of(int t, int d) {
  if (t == 0) return 3 * d;
  if (t == 2) return 3 * d + 1;
  if (t == 3) return 3 * d + 2;
  if (t == 1) return 150000 + d;
  return 151000 + d;  // t4
}

// ------------------------------------------------ fp32 -> bf16 (pad K to Kp)
__global__ void conv_pad(const float* __restrict__ in, unsigned short* __restrict__ out,
                         int M, int K, int Kp) {
  int i = blockIdx.x * blockDim.x + threadIdx.x;
  if (i >= M * Kp) return;
  int r = i / Kp, c = i - r * Kp;
  out[i] = (c < K) ? f2b(in[(size_t)r * K + c]) : (unsigned short)0;
}

// ---------------------- W[K x N] fp32 -> Wt[N x Kp] bf16 (batched, zero-pad K)
__global__ void transpose_w(const float* __restrict__ W, unsigned short* __restrict__ Wt,
                            int K, int N, int Kp, int nmat) {
  int i = blockIdx.x * blockDim.x + threadIdx.x;
  int per = N * Kp;
  if (i >= nmat * per) return;
  int b = i / per, rem = i - b * per;
  int n = rem / Kp, k = rem - n * Kp;
  Wt[i] = (k < K) ? f2b(W[(size_t)b * K * N + (size_t)k * N + n]) : (unsigned short)0;
}

// --------------------------------------------- plain bf16 MFMA GEMM (N=128)
template <int KC>   // K = KC*32
__global__ __launch_bounds__(256) void gemm_mfma(
    const unsigned short* __restrict__ A, const unsigned short* __restrict__ Bt,
    const float* __restrict__ bias, float* __restrict__ Cf,
    unsigned short* __restrict__ Cb, int M) {
  const int K = KC * 32;
  int w = blockIdx.x * 4 + (threadIdx.x >> 6);
  int m0 = w * 16;
  if (m0 >= M) return;
  int lane = threadIdx.x & 63;
  int l16 = lane & 15, quad = lane >> 4;
  int arow = m0 + l16; if (arow >= M) arow = M - 1;
  bf16x8 af[KC];
#pragma unroll
  for (int kc = 0; kc < KC; kc++) {
    int4 raw = *(const int4*)(A + (size_t)arow * K + kc * 32 + quad * 8);
    af[kc] = __builtin_bit_cast(bf16x8, raw);
  }
#pragma unroll
  for (int nt = 0; nt < 8; nt++) {
    int col = nt * 16 + l16;
    f32x4 acc = {0.f, 0.f, 0.f, 0.f};
#pragma unroll
    for (int kc = 0; kc < KC; kc++) {
      int4 braw = *(const int4*)(Bt + (size_t)col * K + kc * 32 + quad * 8);
      acc = __builtin_amdgcn_mfma_f32_16x16x32_bf16(
          af[kc], __builtin_bit_cast(bf16x8, braw), acc, 0, 0, 0);
    }
    float bv = bias ? bias[col] : 0.f;
#pragma unroll
    for (int r = 0; r < 4; r++) {
      int row = m0 + quad * 4 + r;
      if (row < M) {
        float v = acc[r] + bv;
        if (Cf) Cf[(size_t)row * HID + col] = v;
        if (Cb) Cb[(size_t)row * HID + col] = f2b(v);
      }
    }
  }
}

// ------------------- batched relation GEMM: xs = x@Wg (bf16 out), no epilogue
struct GemmJobs {
  const unsigned short* A[5];
  const unsigned short* Bt[5];
  unsigned short* Cb[5];
  int M[5];
  int bpref[6];
};

__global__ __launch_bounds__(256) void gemm_batched(GemmJobs J) {
  int b = blockIdx.x;
  int t = 0;
  while (t < 4 && b >= J.bpref[t + 1]) t++;
  const int M = J.M[t];
  int strip = (b - J.bpref[t]) * 4 + (threadIdx.x >> 6);
  int m0 = strip * 16;
  if (m0 >= M) return;
  int lane = threadIdx.x & 63;
  int l16 = lane & 15, quad = lane >> 4;
  const unsigned short* A = J.A[t];
  const unsigned short* Bt = J.Bt[t];
  unsigned short* Cb = J.Cb[t];
  int arow = m0 + l16; if (arow >= M) arow = M - 1;
  bf16x8 af[4];
#pragma unroll
  for (int kc = 0; kc < 4; kc++) {
    int4 raw = *(const int4*)(A + (size_t)arow * HID + kc * 32 + quad * 8);
    af[kc] = __builtin_bit_cast(bf16x8, raw);
  }
#pragma unroll
  for (int nt = 0; nt < 8; nt++) {
    int col = nt * 16 + l16;
    f32x4 acc = {0.f, 0.f, 0.f, 0.f};
#pragma unroll
    for (int kc = 0; kc < 4; kc++) {
      int4 braw = *(const int4*)(Bt + (size_t)col * HID + kc * 32 + quad * 8);
      acc = __builtin_amdgcn_mfma_f32_16x16x32_bf16(
          af[kc], __builtin_bit_cast(bf16x8, braw), acc, 0, 0, 0);
    }
#pragma unroll
    for (int r = 0; r < 4; r++) {
      int row = m0 + quad * 4 + r;
      if (row < M) Cb[(size_t)row * HID + col] = f2b(acc[r]);
    }
  }
}

// ------------------------------------------------- fold attention vectors
// S[lt,h,k] = sum_c Wg[k][hC+c]*att_s[hC+c]; D likewise; w32/cvec edge fold.
__global__ void fold_kernel(const float* __restrict__ Wg, const float* __restrict__ att_s,
                            const float* __restrict__ att_d, const float* __restrict__ Wge,
                            const float* __restrict__ att_e, const float* __restrict__ Wep,
                            const float* __restrict__ bep,
                            float* __restrict__ S, float* __restrict__ D,
                            float* __restrict__ w32, float* __restrict__ cvec) {
  int idx = blockIdx.x;          // (l*5+t)*8 + h
  int h = idx & 7, lt = idx >> 3;
  int l = lt / 5;
  int H = (l < 2) ? 8 : 1, C = HID / H;
  if (h >= H) return;
  int k = threadIdx.x;           // 0..127
  int t = lt % 5;
  const float* wg  = Wg  + (size_t)lt * HID * HID;
  const float* wge = Wge + (size_t)lt * HID * HID;
  const float* as_ = att_s + (size_t)lt * HID + h * C;
  const float* ad_ = att_d + (size_t)lt * HID + h * C;
  const float* ae_ = att_e + (size_t)lt * HID + h * C;
  float s = 0.f, d = 0.f, v = 0.f;
  for (int c = 0; c < C; c++) {
    float wr = wg[(size_t)k * HID + h * C + c];
    s += wr * as_[c];
    d += wr * ad_[c];
    v += wge[(size_t)k * HID + h * C + c] * ae_[c];
  }
  S[(size_t)idx * HID + k] = s;
  D[(size_t)idx * HID + k] = d;
  __shared__ float vs[HID];
  vs[k] = v;
  __syncthreads();
  if (k < 32) {
    const float* wp = Wep + (size_t)t * 32 * HID + (size_t)k * HID;
    float a = 0.f;
    for (int j = 0; j < HID; j++) a += wp[j] * vs[j];
    w32[(size_t)idx * 32 + k] = a;
  }
  if (k == 32) {
    const float* bp = bep + (size_t)t * HID;
    float a = 0.f;
    for (int j = 0; j < HID; j++) a += bp[j] * vs[j];
    cvec[idx] = a;
  }
}

// ---- a_s/a_d via folded vectors, one wave per global node, bf16 x input
template <int H>
__global__ void rowdot_sd(const unsigned short* __restrict__ xb,
                          const float* __restrict__ Sv, const float* __restrict__ Dv,
                          float* __restrict__ as_all, float* __restrict__ ad_all) {
  int g = (int)((blockIdx.x * (size_t)blockDim.x + threadIdx.x) >> 6);
  int lane = threadIdx.x & 63;
  if (g >= kNTot) return;
  unsigned u = ((const unsigned*)(xb + (size_t)g * HID))[lane];
  float xlo = __uint_as_float(u << 16);          // col 2*lane
  float xhi = __uint_as_float(u & 0xFFFF0000u);  // col 2*lane+1
  const float* vb[6]; float* op_[6]; int ns;
  if (g < 50000) {
    size_t i = g;
    vb[0] = Sv + 0 * 8 * HID;  op_[0] = as_all + (size_t)kRoff[0] * H + i * H;    // t0 a_s
    vb[1] = Sv + 1 * 8 * HID;  op_[1] = as_all + (size_t)kRoff[1] * H + i * H;    // t1 a_s
    vb[2] = Sv + 4 * 8 * HID;  op_[2] = as_all + (size_t)kRoff[4] * H + i * H;    // t4 a_s
    vb[3] = Dv + 0 * 8 * HID;  op_[3] = ad_all + (size_t)kAdoff[0] * H + i * H;   // t0 a_d
    vb[4] = Dv + 2 * 8 * HID;  op_[4] = ad_all + (size_t)kAdoff[2] * H + i * H;   // t2 a_d
    vb[5] = Dv + 3 * 8 * HID;  op_[5] = ad_all + (size_t)kAdoff[3] * H + i * H;   // t3 a_d
    ns = 6;
  } else if (g < 51000) {
    size_t n = g - 50000;
    vb[0] = Sv + 2 * 8 * HID;  op_[0] = as_all + (size_t)kRoff[2] * H + n * H;    // t2 a_s
    vb[1] = Dv + 1 * 8 * HID;  op_[1] = ad_all + (size_t)kAdoff[1] * H + n * H;   // t1 a_d
    ns = 2;
  } else {
    size_t n = g - 51000;
    vb[0] = Sv + 3 * 8 * HID;  op_[0] = as_all + (size_t)kRoff[3] * H + n * H;    // t3 a_s
    vb[1] = Dv + 4 * 8 * HID;  op_[1] = ad_all + (size_t)kAdoff[4] * H + n * H;   // t4 a_d
    ns = 2;
  }
  for (int s = 0; s < ns; s++) {
#pragma unroll
    for (int h = 0; h < H; h++) {
      float2 vv = ((const float2*)(vb[s] + (size_t)h * HID))[lane];
      float a = xlo * vv.x + xhi * vv.y;
#pragma unroll
      for (int off = 1; off < 64; off <<= 1) a += __shfl_xor(a, off);
      if (lane == 0) op_[s][h] = a;
    }
  }
}

// ------------------------------------------------------------ CSR building
struct EdgeJobs {
  const int* src[5]; const int* dst[5];
};

__global__ void hist_b(EdgeJobs J, int* __restrict__ cnt) {
  int e = blockIdx.x * 256 + threadIdx.x;
  if (e >= kETot) return;
  int t = 0;
  while (t < 4 && e >= kEoff[t + 1]) t++;
  int d = J.dst[t][e - kEoff[t]];
  atomicAdd(&cnt[seg_of(t, d)], 1);
}

__global__ void scatter_b(EdgeJobs J, int* __restrict__ cursor,
                          int* __restrict__ perm, int* __restrict__ ssrc) {
  int e = blockIdx.x * 256 + threadIdx.x;
  if (e >= kETot) return;
  int t = 0;
  while (t < 4 && e >= kEoff[t + 1]) t++;
  int el = e - kEoff[t];
  int d = J.dst[t][el];
  int p = atomicAdd(&cursor[seg_of(t, d)], 1);
  perm[e] = p;
  ssrc[p] = J.src[t][el] + kRoff[t];
}

__global__ void scan_blocks(const int* __restrict__ in, int* __restrict__ out,
                            int* __restrict__ bsums, int n) {
  __shared__ int sh[256];
  int t = threadIdx.x;
  int base = blockIdx.x * 1024 + t * 4;
  int v[4]; int s = 0;
#pragma unroll
  for (int j = 0; j < 4; j++) { v[j] = (base + j < n) ? in[base + j] : 0; s += v[j]; }
  sh[t] = s;
  __syncthreads();
  for (int off = 1; off < 256; off <<= 1) {
    int x = (t >= off) ? sh[t - off] : 0;
    __syncthreads();
    sh[t] += x;
    __syncthreads();
  }
  int run = sh[t] - s;
#pragma unroll
  for (int j = 0; j < 4; j++) { if (base + j < n) out[base + j] = run; run += v[j]; }
  if (t == 255) bsums[blockIdx.x] = sh[255];
}

__global__ void scan_carry(int* bsums, int nb, int* sentinel) {
  if (threadIdx.x == 0 && blockIdx.x == 0) {
    int run = 0;
    for (int b = 0; b < nb; b++) { int x = bsums[b]; bsums[b] = run; run += x; }
    *sentinel = run;
  }
}

__global__ void scan_add(int* __restrict__ out, const int* __restrict__ bsums, int n) {
  int base = blockIdx.x * 1024 + threadIdx.x * 4;
  int c = bsums[blockIdx.x];
#pragma unroll
  for (int j = 0; j < 4; j++) if (base + j < n) out[base + j] += c;
}

__global__ void copy_k(const int* __restrict__ in, int* __restrict__ out, int n) {
  int i = blockIdx.x * blockDim.x + threadIdx.x;
  if (i < n) out[i] = in[i];
}

// ----------------------- batched pass A: logits into global CSR positions
struct PassAJobs {
  const int* src[5]; const int* dst[5]; const int* perm[5];
  const float* ea[5]; const float* as_[5]; const float* ad_[5];
  const float* w32[5]; const float* cv[5];
  int E[5]; int bpref[6];
};

template <int H>
__global__ __launch_bounds__(256) void pass_a_b(PassAJobs J, float* __restrict__ logits) {
  int b = blockIdx.x;
  int t = 0;
  while (t < 4 && b >= J.bpref[t + 1]) t++;
  __shared__ float w[H][32];
  __shared__ float cc[H];
  for (int i = threadIdx.x; i < H * 32; i += 256) w[i >> 5][i & 31] = J.w32[t][i];
  if (threadIdx.x < H) cc[threadIdx.x] = J.cv[t][threadIdx.x];
  __syncthreads();
  int e = (b - J.bpref[t]) * 256 + threadIdx.x;
  if (e >= J.E[t]) return;
  int s = J.src[t][e], d = J.dst[t][e], pe = J.perm[t][e];
  const float* asp = J.as_[t] + (size_t)s * H;
  const float* adp = J.ad_[t] + (size_t)d * H;
  float x[32];
  const float4* p = (const float4*)(J.ea[t] + (size_t)e * 32);
#pragma unroll
  for (int i = 0; i < 8; i++) {
    float4 v = p[i];
    x[4 * i] = v.x; x[4 * i + 1] = v.y; x[4 * i + 2] = v.z; x[4 * i + 3] = v.w;
  }
#pragma unroll
  for (int h = 0; h < H; h++) {
    float a = cc[h];
#pragma unroll
    for (int k = 0; k < 32; k++) a += x[k] * w[h][k];
    float v = a + asp[h] + adp[h];
    v = v > 0.f ? v : 0.2f * v;
    logits[(size_t)pe * H + h] = v;
  }
}

// ------- segment softmax per (dst,relation) sub-segment, in place -> alpha
template <int H>
__global__ void softmax_k(const int* __restrict__ rs, float* __restrict__ lg) {
  int g = (int)((blockIdx.x * (size_t)blockDim.x + threadIdx.x) >> 6);
  int lane = threadIdx.x & 63;
  if (g >= kSeg) return;
  int start = rs[g], end = rs[g + 1];
  int n = (end - start) * H;
  if (n == 0) return;
  float* L = lg + (size_t)start * H;
  float m = -3.0e38f;
  for (int idx = lane; idx < n; idx += 64) m = fmaxf(m, L[idx]);
  if (H == 8) {
    m = fmaxf(m, __shfl_xor(m, 8));
    m = fmaxf(m, __shfl_xor(m, 16));
    m = fmaxf(m, __shfl_xor(m, 32));
  } else {
#pragma unroll
    for (int off = 1; off < 64; off <<= 1) m = fmaxf(m, __shfl_xor(m, off));
  }
  float s = 0.f;
  for (int idx = lane; idx < n; idx += 64) {
    float ex = __expf(L[idx] - m);
    L[idx] = ex;
    s += ex;
  }
  if (H == 8) {
    s += __shfl_xor(s, 8);
    s += __shfl_xor(s, 16);
    s += __shfl_xor(s, 32);
  } else {
#pragma unroll
    for (int off = 1; off < 64; off <<= 1) s += __shfl_xor(s, off);
  }
  float inv = 1.f / (s + 1e-16f);
  for (int idx = lane; idx < n; idx += 64) L[idx] *= inv;
}

// --------------- unified gather: agg[g] = sum over node's sub-segments of alpha*xs
template <int H>
__global__ void gat_gather_u(const int* __restrict__ rs, const int* __restrict__ ssrc,
                             const float* __restrict__ alpha,
                             const unsigned short* __restrict__ xs,
                             float* __restrict__ agg) {
  int g = (int)((blockIdx.x * (size_t)blockDim.x + threadIdx.x) >> 6);
  int lane = threadIdx.x & 63;
  if (g >= kNTot) return;
  int start, end;
  if (g < 50000)      { start = rs[3 * g];              end = rs[3 * g + 3]; }
  else if (g < 51000) { int m = g - 50000; start = rs[150000 + m]; end = rs[150001 + m]; }
  else                { int j = g - 51000; start = rs[151000 + j]; end = rs[151001 + j]; }
  int deg = end - start;
  int l16 = lane & 15, quad = lane >> 4;
  int h = (H == 8) ? (l16 >> 1) : 0;
  float acc[8] = {0.f, 0.f, 0.f, 0.f, 0.f, 0.f, 0.f, 0.f};
  for (int base = 0; base < deg; base += 64) {
    int nchunk = deg - base; if (nchunk > 64) nchunk = 64;
    int sv = (lane < nchunk) ? ssrc[start + base + lane] : 0;
    for (int i = 0; i < nchunk; i += 4) {
      int e = i + quad;
      bool act = e < nchunk;
      int s = __shfl(sv, act ? e : 0);
      float w = act ? alpha[(size_t)(start + base + e) * H + h] : 0.f;
      int4 raw = *(const int4*)(xs + (size_t)s * HID + l16 * 8);
      unsigned ua[4] = {(unsigned)raw.x, (unsigned)raw.y, (unsigned)raw.z, (unsigned)raw.w};
#pragma unroll
      for (int j = 0; j < 4; j++) {
        acc[2 * j]     += w * __uint_as_float(ua[j] << 16);
        acc[2 * j + 1] += w * __uint_as_float(ua[j] & 0xFFFF0000u);
      }
    }
  }
#pragma unroll
  for (int j = 0; j < 8; j++) {
    acc[j] += __shfl_xor(acc[j], 16);
    acc[j] += __shfl_xor(acc[j], 32);
  }
  if (quad == 0) {
    float* p = agg + (size_t)g * HID + l16 * 8;
    *(float4*)p = make_float4(acc[0], acc[1], acc[2], acc[3]);
    *(float4*)(p + 4) = make_float4(acc[4], acc[5], acc[6], acc[7]);
  }
}

// ------------------------------------------------- BatchNorm column stats
__global__ void colstats_b(const float* __restrict__ x, float* __restrict__ stats) {
  static constexpr int bpref[4] = {0, 384, 400, 448};
  static constexpr int rowoff[4] = {0, 50000, 51000, 56000};
  int b = blockIdx.x;
  int t = 0;
  while (t < 2 && b >= bpref[t + 1]) t++;
  int bl = b - bpref[t], nb = bpref[t + 1] - bpref[t];
  int tid = threadIdx.x;
  int col = tid & 127, half = tid >> 7;
  float s = 0.f, q = 0.f;
  for (int r = rowoff[t] + bl * 2 + half; r < rowoff[t + 1]; r += nb * 2) {
    float v = x[(size_t)r * HID + col];
    s += v; q += v * v;
  }
  __shared__ float ls[256], lq[256];
  ls[tid] = s; lq[tid] = q;
  __syncthreads();
  if (tid < 128) {
    s = ls[tid] + ls[tid + 128];
    q = lq[tid] + lq[tid + 128];
    unsafeAtomicAdd(&stats[t * 256 + col], s);
    unsafeAtomicAdd(&stats[t * 256 + 128 + col], q);
  }
}

// --- BN apply + ReLU + residual: fp32 agg (in-place -> new x) + bf16 shadow
__global__ void bn_apply_b(float* __restrict__ agg, const float* __restrict__ xold,
                           unsigned short* __restrict__ xnb, const float* __restrict__ stats,
                           const float* __restrict__ gammaL, const float* __restrict__ betaL,
                           int relu) {
  size_t i = blockIdx.x * (size_t)blockDim.x + threadIdx.x;
  if (i >= (size_t)kNTot * 32) return;
  int row = (int)(i >> 5);
  int t = (row < 50000) ? 0 : (row < 51000 ? 1 : 2);
  float invN = (t == 0) ? (1.f / 50000.f) : (t == 1 ? (1.f / 1000.f) : (1.f / 5000.f));
  const float* st = stats + t * 256;
  const float* gm = gammaL + t * HID;
  const float* bt = betaL + t * HID;
  int c4 = ((int)(i & 31)) * 4;
  float4 av = ((const float4*)agg)[i];
  float4 xv = ((const float4*)xold)[i];
  float a[4] = {av.x, av.y, av.z, av.w};
  float xo[4] = {xv.x, xv.y, xv.z, xv.w};
  float o[4];
#pragma unroll
  for (int j = 0; j < 4; j++) {
    int c = c4 + j;
    float mu = st[c] * invN;
    float var = st[128 + c] * invN - mu * mu;
    float g = gm[c] * rsqrtf(var + 1e-5f);
    float v = (a[j] - mu) * g + bt[c];
    if (relu) v = fmaxf(v, 0.f);
    o[j] = v + xo[j];
  }
  ((float4*)agg)[i] = make_float4(o[0], o[1], o[2], o[3]);
  ((ushort4*)xnb)[i] = make_ushort4(f2b(o[0]), f2b(o[1]), f2b(o[2]), f2b(o[3]));
}

// ============================================================== host driver
extern "C" void kernel_launch(void* const* d_in, const int* in_sizes, int n_in,
                              void* d_out, int out_size, void* d_ws, size_t ws_size,
                              hipStream_t stream) {
  const float* x_in[3] = {(const float*)d_in[0], (const float*)d_in[1], (const float*)d_in[2]};
  const int* ei[5];
  const float* ea[5];
  for (int t = 0; t < 5; t++) {
    ei[t] = (const int*)d_in[3 + 2 * t];
    ea[t] = (const float*)d_in[4 + 2 * t];
  }
  const float* Wn[3]  = {(const float*)d_in[13], (const float*)d_in[15], (const float*)d_in[17]};
  const float* bnb[3] = {(const float*)d_in[14], (const float*)d_in[16], (const float*)d_in[18]};
  const float* Wep   = (const float*)d_in[19];
  const float* bep   = (const float*)d_in[20];
  const float* Wg    = (const float*)d_in[21];
  const float* att_s = (const float*)d_in[22];
  const float* att_d = (const float*)d_in[23];
  const float* Wge   = (const float*)d_in[24];
  const float* att_e = (const float*)d_in[25];
  // d_in[26] = bg: cancelled exactly by BatchNorm mean-subtraction; unused.
  const float* gamma = (const float*)d_in[27];
  const float* beta  = (const float*)d_in[28];
  const float* Wo    = (const float*)d_in[29];
  const float* bo    = (const float*)d_in[30];

  float* ws = (float*)d_ws;
  size_t off = 0;
  auto alloc = [&](size_t n) { size_t o = off; off += (n + 255) & ~(size_t)255; return o; };
  auto allocb = [&](size_t n) { return alloc((n + 1) / 2); };

  float* bufA = ws + alloc((size_t)kNTot * HID);   // fp32 x (residual chain)
  float* bufB = ws + alloc((size_t)kNTot * HID);   // fp32 agg / next x
  unsigned short* xcurb = (unsigned short*)(ws + allocb((size_t)kNTot * HID));
  unsigned short* xs_all = (unsigned short*)(ws + allocb((size_t)kRTot * HID));
  unsigned short* WgT  = (unsigned short*)(ws + allocb((size_t)15 * HID * HID));
  unsigned short* WoT  = (unsigned short*)(ws + allocb((size_t)HID * HID));
  unsigned short* WnT_op  = (unsigned short*)(ws + allocb((size_t)HID * 64));
  unsigned short* WnT_ma  = (unsigned short*)(ws + allocb((size_t)HID * 32));
  unsigned short* WnT_job = (unsigned short*)(ws + allocb((size_t)HID * 32));
  float* Sv     = ws + alloc((size_t)15 * 8 * HID);
  float* Dv     = ws + alloc((size_t)15 * 8 * HID);
  float* w32    = ws + alloc((size_t)15 * 8 * 32);
  float* cv     = ws + alloc((size_t)15 * 8);
  float* stats  = ws + alloc((size_t)3 * 256);
  float* as_all = ws + alloc((size_t)kRTot * 8);
  float* ad_all = ws + alloc((size_t)kAdTot * 8);
  float* logits = ws + alloc((size_t)kETot * 8 + 64);
  int* rs_all   = (int*)(ws + alloc((size_t)kSeg + 8));
  int* perm_all = (int*)(ws + alloc((size_t)kETot));
  int* ssrc_all = (int*)(ws + alloc((size_t)kETot));
  // aliases: xinb_* live inside xs_all (consumed before xs_all is written);
  // cnt/cursor/bsums live inside logits (CSR build precedes first logit write)
  unsigned short* xinb_op  = xs_all;                          // 3.2M ushorts
  unsigned short* xinb_ma  = xs_all + 3200000;                // 32k ushorts
  unsigned short* xinb_job = xs_all + 3232000;                // 160k ushorts
  int* cnt    = (int*)logits;
  int* cursor = (int*)(logits + 156032);
  int* bsums  = (int*)(logits + 312064);
  (void)ws_size; (void)in_sizes; (void)n_in; (void)out_size;

  float* xcur = bufA;
  float* agg  = bufB;

  // -------- unified CSR over (dst,relation) sub-segments, built once
  EdgeJobs EJ;
  for (int t = 0; t < 5; t++) { EJ.src[t] = ei[t]; EJ.dst[t] = ei[t] + kEsz[t]; }
  hipMemsetAsync(cnt, 0, (size_t)kSeg * 4, stream);
  hist_b<<<(kETot + 255) / 256, 256, 0, stream>>>(EJ, cnt);
  int nb = (kSeg + 1023) / 1024;
  scan_blocks<<<nb, 256, 0, stream>>>(cnt, rs_all, bsums, kSeg);
  scan_carry<<<1, 64, 0, stream>>>(bsums, nb, rs_all + kSeg);
  scan_add<<<nb, 256, 0, stream>>>(rs_all, bsums, kSeg);
  copy_k<<<(kSeg + 255) / 256, 256, 0, stream>>>(rs_all, cursor, kSeg);
  scatter_b<<<(kETot + 255) / 256, 256, 0, stream>>>(EJ, cursor, perm_all, ssrc_all);

  // -------- bf16 conversions
  conv_pad<<<(kNOp * 64 + 255) / 256, 256, 0, stream>>>(x_in[0], xinb_op, kNOp, 64, 64);
  conv_pad<<<(kNMa * 32 + 255) / 256, 256, 0, stream>>>(x_in[1], xinb_ma, kNMa, 32, 32);
  conv_pad<<<(kNJob * 32 + 255) / 256, 256, 0, stream>>>(x_in[2], xinb_job, kNJob, 16, 32);
  transpose_w<<<(HID * 64 + 255) / 256, 256, 0, stream>>>(Wn[0], WnT_op, 64, HID, 64, 1);
  transpose_w<<<(HID * 32 + 255) / 256, 256, 0, stream>>>(Wn[1], WnT_ma, 32, HID, 32, 1);
  transpose_w<<<(HID * 32 + 255) / 256, 256, 0, stream>>>(Wn[2], WnT_job, 16, HID, 32, 1);
  transpose_w<<<(15 * HID * HID + 255) / 256, 256, 0, stream>>>(Wg, WgT, HID, HID, HID, 15);
  transpose_w<<<(HID * HID + 255) / 256, 256, 0, stream>>>(Wo, WoT, HID, HID, HID, 1);
  fold_kernel<<<120, 128, 0, stream>>>(Wg, att_s, att_d, Wge, att_e, Wep, bep,
                                       Sv, Dv, w32, cv);

  // -------- node input projections (fp32 x + bf16 shadow)
  gemm_mfma<2><<<((kNOp + 15) / 16 + 3) / 4, 256, 0, stream>>>(
      xinb_op, WnT_op, bnb[0], xcur, xcurb, kNOp);
  gemm_mfma<1><<<((kNMa + 15) / 16 + 3) / 4, 256, 0, stream>>>(
      xinb_ma, WnT_ma, bnb[1], xcur + (size_t)50000 * HID, xcurb + (size_t)50000 * HID, kNMa);
  gemm_mfma<1><<<((kNJob + 15) / 16 + 3) / 4, 256, 0, stream>>>(
      xinb_job, WnT_job, bnb[2], xcur + (size_t)51000 * HID, xcurb + (size_t)51000 * HID, kNJob);

  static constexpr int gemmBpref[6]  = {0, 782, 1564, 1580, 1659, 2441};
  static constexpr int passABpref[6] = {0, 587, 978, 1565, 1956, 2347};
  static constexpr int nsRel[5] = {50000, 50000, 1000, 5000, 50000};

  for (int l = 0; l < 3; l++) {
    int H = (l < 2) ? 8 : 1;

    GemmJobs GJ;
    for (int t = 0; t < 5; t++) {
      int lt = l * 5 + t;
      GJ.A[t]  = xcurb + (size_t)kNodeOff[kSrcT[t]] * HID;
      GJ.Bt[t] = WgT + (size_t)lt * HID * HID;
      GJ.Cb[t] = xs_all + (size_t)kRoff[t] * HID;
      GJ.M[t] = nsRel[t];
      GJ.bpref[t] = gemmBpref[t];
    }
    GJ.bpref[5] = gemmBpref[5];
    gemm_batched<<<gemmBpref[5], 256, 0, stream>>>(GJ);

    if (H == 8)
      rowdot_sd<8><<<((size_t)kNTot * 64 + 255) / 256, 256, 0, stream>>>(
          xcurb, Sv + (size_t)l * 5 * 8 * HID, Dv + (size_t)l * 5 * 8 * HID, as_all, ad_all);
    else
      rowdot_sd<1><<<((size_t)kNTot * 64 + 255) / 256, 256, 0, stream>>>(
          xcurb, Sv + (size_t)l * 5 * 8 * HID, Dv + (size_t)l * 5 * 8 * HID, as_all, ad_all);

    PassAJobs PJ;
    for (int t = 0; t < 5; t++) {
      int lt = l * 5 + t;
      PJ.src[t] = ei[t]; PJ.dst[t] = ei[t] + kEsz[t];
      PJ.perm[t] = perm_all + kEoff[t];
      PJ.ea[t] = ea[t];
      PJ.as_[t] = as_all + (size_t)kRoff[t] * H;
      PJ.ad_[t] = ad_all + (size_t)kAdoff[t] * H;
      PJ.w32[t] = w32 + (size_t)lt * 8 * 32;
      PJ.cv[t]  = cv + (size_t)lt * 8;
      PJ.E[t] = kEsz[t];
      PJ.bpref[t] = passABpref[t];
    }
    PJ.bpref[5] = passABpref[5];
    if (H == 8) pass_a_b<8><<<passABpref[5], 256, 0, stream>>>(PJ, logits);
    else        pass_a_b<1><<<passABpref[5], 256, 0, stream>>>(PJ, logits);

    if (H == 8) {
      softmax_k<8><<<((size_t)kSeg * 64 + 255) / 256, 256, 0, stream>>>(rs_all, logits);
      gat_gather_u<8><<<((size_t)kNTot * 64 + 255) / 256, 256, 0, stream>>>(
          rs_all, ssrc_all, logits, xs_all, agg);
    } else {
      softmax_k<1><<<((size_t)kSeg * 64 + 255) / 256, 256, 0, stream>>>(rs_all, logits);
      gat_gather_u<1><<<((size_t)kNTot * 64 + 255) / 256, 256, 0, stream>>>(
          rs_all, ssrc_all, logits, xs_all, agg);
    }

    hipMemsetAsync(stats, 0, 3 * 256 * 4, stream);
    colstats_b<<<448, 256, 0, stream>>>(agg, stats);
    bn_apply_b<<<(unsigned)(((size_t)kNTot * 32 + 255) / 256), 256, 0, stream>>>(
        agg, xcur, xcurb, stats, gamma + (size_t)l * 3 * HID, beta + (size_t)l * 3 * HID,
        (l < 2) ? 1 : 0);
    float* tmp = xcur; xcur = agg; agg = tmp;   // agg now holds new fp32 x
  }

  gemm_mfma<4><<<((kNOp + 15) / 16 + 3) / 4, 256, 0, stream>>>(
      xcurb, WoT, bo, (float*)d_out, nullptr, kNOp);
}

// Round 8
// 1035.713 us; speedup vs baseline: 5.3730x; 1.3343x over previous
//
#include <hip/hip_runtime.h>
#include <cstdint>

#define HID 128

static constexpr int kNOp = 50000, kNMa = 1000, kNJob = 5000;
static constexpr int kNTot = 56000;                 // op | ma | job global node space
static constexpr int kETot = 600000;
static constexpr int kSeg = 156000;                 // (dst,relation) sub-segments
static constexpr int kEsz[5]   = {150000, 100000, 150000, 100000, 100000};
static constexpr int kSrcT[5]  = {0, 0, 1, 2, 0};
static constexpr int kDstT[5]  = {0, 1, 0, 0, 2};
static constexpr int kNodeOff[3] = {0, 50000, 51000};
static constexpr int kEoff[6]  = {0, 150000, 250000, 400000, 500000, 600000};
static constexpr int kRoff[5]  = {0, 50000, 100000, 101000, 106000};  // xs_all row offset (src counts)
static constexpr int kRTot = 156000;

typedef __attribute__((ext_vector_type(8))) __bf16 bf16x8;
typedef __attribute__((ext_vector_type(4))) float f32x4;

__device__ inline unsigned short f2b(float f) {
  unsigned u = __float_as_uint(f);
  unsigned r = (u + 0x7FFFu + ((u >> 16) & 1u)) >> 16;
  return (unsigned short)r;
}
__device__ inline float b2f(unsigned short u) {
  return __uint_as_float(((unsigned)u) << 16);
}

// (dst,relation) -> softmax sub-segment id; op sub-segments contiguous per node
__device__ inline int seg_of(int t, int d) {
  if (t == 0) return 3 * d;
  if (t == 2) return 3 * d + 1;
  if (t == 3) return 3 * d + 2;
  if (t == 1) return 150000 + d;
  return 151000 + d;  // t4
}

// ------------------------------------------------ fp32 -> bf16 (pad K to Kp)
__global__ void conv_pad(const float* __restrict__ in, unsigned short* __restrict__ out,
                         int M, int K, int Kp) {
  int i = blockIdx.x * blockDim.x + threadIdx.x;
  if (i >= M * Kp) return;
  int r = i / Kp, c = i - r * Kp;
  out[i] = (c < K) ? f2b(in[(size_t)r * K + c]) : (unsigned short)0;
}

// ---------------------- W[K x N] fp32 -> Wt[N x Kp] bf16 (batched, zero-pad K)
__global__ void transpose_w(const float* __restrict__ W, unsigned short* __restrict__ Wt,
                            int K, int N, int Kp, int nmat) {
  int i = blockIdx.x * blockDim.x + threadIdx.x;
  int per = N * Kp;
  if (i >= nmat * per) return;
  int b = i / per, rem = i - b * per;
  int n = rem / Kp, k = rem - n * Kp;
  Wt[i] = (k < K) ? f2b(W[(size_t)b * K * N + (size_t)k * N + n]) : (unsigned short)0;
}

// --------------------------------------------- plain bf16 MFMA GEMM (N=128)
template <int KC>   // K = KC*32
__global__ __launch_bounds__(256) void gemm_mfma(
    const unsigned short* __restrict__ A, const unsigned short* __restrict__ Bt,
    const float* __restrict__ bias, float* __restrict__ Cf,
    unsigned short* __restrict__ Cb, int M) {
  const int K = KC * 32;
  int w = blockIdx.x * 4 + (threadIdx.x >> 6);
  int m0 = w * 16;
  if (m0 >= M) return;
  int lane = threadIdx.x & 63;
  int l16 = lane & 15, quad = lane >> 4;
  int arow = m0 + l16; if (arow >= M) arow = M - 1;
  bf16x8 af[KC];
#pragma unroll
  for (int kc = 0; kc < KC; kc++) {
    int4 raw = *(const int4*)(A + (size_t)arow * K + kc * 32 + quad * 8);
    af[kc] = __builtin_bit_cast(bf16x8, raw);
  }
#pragma unroll
  for (int nt = 0; nt < 8; nt++) {
    int col = nt * 16 + l16;
    f32x4 acc = {0.f, 0.f, 0.f, 0.f};
#pragma unroll
    for (int kc = 0; kc < KC; kc++) {
      int4 braw = *(const int4*)(Bt + (size_t)col * K + kc * 32 + quad * 8);
      acc = __builtin_amdgcn_mfma_f32_16x16x32_bf16(
          af[kc], __builtin_bit_cast(bf16x8, braw), acc, 0, 0, 0);
    }
    float bv = bias ? bias[col] : 0.f;
#pragma unroll
    for (int r = 0; r < 4; r++) {
      int row = m0 + quad * 4 + r;
      if (row < M) {
        float v = acc[r] + bv;
        if (Cf) Cf[(size_t)row * HID + col] = v;
        if (Cb) Cb[(size_t)row * HID + col] = f2b(v);
      }
    }
  }
}

// ------------------- batched relation GEMM: xs = x@Wg (bf16 out)
struct GemmJobs {
  const unsigned short* A[5];
  const unsigned short* Bt[5];
  unsigned short* Cb[5];
  int M[5];
  int bpref[6];
};

__global__ __launch_bounds__(256) void gemm_batched(GemmJobs J) {
  int b = blockIdx.x;
  int t = 0;
  while (t < 4 && b >= J.bpref[t + 1]) t++;
  const int M = J.M[t];
  int strip = (b - J.bpref[t]) * 4 + (threadIdx.x >> 6);
  int m0 = strip * 16;
  if (m0 >= M) return;
  int lane = threadIdx.x & 63;
  int l16 = lane & 15, quad = lane >> 4;
  const unsigned short* A = J.A[t];
  const unsigned short* Bt = J.Bt[t];
  unsigned short* Cb = J.Cb[t];
  int arow = m0 + l16; if (arow >= M) arow = M - 1;
  bf16x8 af[4];
#pragma unroll
  for (int kc = 0; kc < 4; kc++) {
    int4 raw = *(const int4*)(A + (size_t)arow * HID + kc * 32 + quad * 8);
    af[kc] = __builtin_bit_cast(bf16x8, raw);
  }
#pragma unroll
  for (int nt = 0; nt < 8; nt++) {
    int col = nt * 16 + l16;
    f32x4 acc = {0.f, 0.f, 0.f, 0.f};
#pragma unroll
    for (int kc = 0; kc < 4; kc++) {
      int4 braw = *(const int4*)(Bt + (size_t)col * HID + kc * 32 + quad * 8);
      acc = __builtin_amdgcn_mfma_f32_16x16x32_bf16(
          af[kc], __builtin_bit_cast(bf16x8, braw), acc, 0, 0, 0);
    }
#pragma unroll
    for (int r = 0; r < 4; r++) {
      int row = m0 + quad * 4 + r;
      if (row < M) Cb[(size_t)row * HID + col] = f2b(acc[r]);
    }
  }
}

// ---------------- AS GEMM: AS[M x NCOL] = x[M x 128] @ VbT^T, fp32 out
template <int NCOL>
__global__ __launch_bounds__(256) void gemm_as(
    const unsigned short* __restrict__ A, const unsigned short* __restrict__ Bt,
    float* __restrict__ out, int M) {
  int w = blockIdx.x * 4 + (threadIdx.x >> 6);
  int m0 = w * 16;
  if (m0 >= M) return;
  int lane = threadIdx.x & 63;
  int l16 = lane & 15, quad = lane >> 4;
  int arow = m0 + l16; if (arow >= M) arow = M - 1;
  bf16x8 af[4];
#pragma unroll
  for (int kc = 0; kc < 4; kc++) {
    int4 raw = *(const int4*)(A + (size_t)arow * HID + kc * 32 + quad * 8);
    af[kc] = __builtin_bit_cast(bf16x8, raw);
  }
#pragma unroll
  for (int nt = 0; nt < NCOL / 16; nt++) {
    int col = nt * 16 + l16;
    f32x4 acc = {0.f, 0.f, 0.f, 0.f};
#pragma unroll
    for (int kc = 0; kc < 4; kc++) {
      int4 braw = *(const int4*)(Bt + (size_t)col * HID + kc * 32 + quad * 8);
      acc = __builtin_amdgcn_mfma_f32_16x16x32_bf16(
          af[kc], __builtin_bit_cast(bf16x8, braw), acc, 0, 0, 0);
    }
#pragma unroll
    for (int r = 0; r < 4; r++) {
      int row = m0 + quad * 4 + r;
      if (row < M) out[(size_t)row * NCOL + col] = acc[r];
    }
  }
}

// ------------------------------------------------- fold attention vectors
// S[lt,h,k] = sum_c Wg[k][hC+c]*att_s[hC+c]; D likewise; w32/cvec edge fold.
__global__ void fold_kernel(const float* __restrict__ Wg, const float* __restrict__ att_s,
                            const float* __restrict__ att_d, const float* __restrict__ Wge,
                            const float* __restrict__ att_e, const float* __restrict__ Wep,
                            const float* __restrict__ bep,
                            float* __restrict__ S, float* __restrict__ D,
                            float* __restrict__ w32, float* __restrict__ cvec) {
  int idx = blockIdx.x;          // (l*5+t)*8 + h
  int h = idx & 7, lt = idx >> 3;
  int l = lt / 5;
  int H = (l < 2) ? 8 : 1, C = HID / H;
  if (h >= H) return;
  int k = threadIdx.x;           // 0..127
  int t = lt % 5;
  const float* wg  = Wg  + (size_t)lt * HID * HID;
  const float* wge = Wge + (size_t)lt * HID * HID;
  const float* as_ = att_s + (size_t)lt * HID + h * C;
  const float* ad_ = att_d + (size_t)lt * HID + h * C;
  const float* ae_ = att_e + (size_t)lt * HID + h * C;
  float s = 0.f, d = 0.f, v = 0.f;
  for (int c = 0; c < C; c++) {
    float wr = wg[(size_t)k * HID + h * C + c];
    s += wr * as_[c];
    d += wr * ad_[c];
    v += wge[(size_t)k * HID + h * C + c] * ae_[c];
  }
  S[(size_t)idx * HID + k] = s;
  D[(size_t)idx * HID + k] = d;
  __shared__ float vs[HID];
  vs[k] = v;
  __syncthreads();
  if (k < 32) {
    const float* wp = Wep + (size_t)t * 32 * HID + (size_t)k * HID;
    float a = 0.f;
    for (int j = 0; j < HID; j++) a += wp[j] * vs[j];
    w32[(size_t)idx * 32 + k] = a;
  }
  if (k == 32) {
    const float* bp = bep + (size_t)t * HID;
    float a = 0.f;
    for (int j = 0; j < HID; j++) a += bp[j] * vs[j];
    cvec[idx] = a;
  }
}

// ------ pack folded S/D vectors into bf16 Bt layout: VbT[l][col][k], col=(v,h)
// v in 0..9: v<5 -> S of relation v; v>=5 -> D of relation v-5. 80 cols/layer.
__global__ void build_vb(const float* __restrict__ Sv, const float* __restrict__ Dv,
                         unsigned short* __restrict__ VbT) {
  int i = blockIdx.x * 256 + threadIdx.x;
  if (i >= 3 * 80 * HID) return;
  int l = i / (80 * HID), rem = i % (80 * HID);
  int col = rem / HID, k = rem % HID;
  int H = (l < 2) ? 8 : 1;
  float val = 0.f;
  if (col < 10 * H) {
    int v = col / H, h = col % H;
    const float* base = (v < 5) ? Sv : Dv;
    int t = (v < 5) ? v : v - 5;
    val = base[((size_t)(l * 5 + t) * 8 + h) * HID + k];
  }
  VbT[i] = f2b(val);
}

// ------------------------------------------------------------ CSR building
struct EdgeJobs {
  const int* src[5]; const int* dst[5];
};

__global__ void hist_b(EdgeJobs J, int* __restrict__ cnt) {
  int e = blockIdx.x * 256 + threadIdx.x;
  if (e >= kETot) return;
  int t = 0;
  while (t < 4 && e >= kEoff[t + 1]) t++;
  int d = J.dst[t][e - kEoff[t]];
  atomicAdd(&cnt[seg_of(t, d)], 1);
}

__global__ void scatter_b(EdgeJobs J, int* __restrict__ cursor,
                          int* __restrict__ perm, int* __restrict__ ssrc) {
  int e = blockIdx.x * 256 + threadIdx.x;
  if (e >= kETot) return;
  int t = 0;
  while (t < 4 && e >= kEoff[t + 1]) t++;
  int el = e - kEoff[t];
  int d = J.dst[t][el];
  int p = atomicAdd(&cursor[seg_of(t, d)], 1);
  perm[e] = p;
  ssrc[p] = J.src[t][el] + kRoff[t];
}

__global__ void scan_blocks(const int* __restrict__ in, int* __restrict__ out,
                            int* __restrict__ bsums, int n) {
  __shared__ int sh[256];
  int t = threadIdx.x;
  int base = blockIdx.x * 1024 + t * 4;
  int v[4]; int s = 0;
#pragma unroll
  for (int j = 0; j < 4; j++) { v[j] = (base + j < n) ? in[base + j] : 0; s += v[j]; }
  sh[t] = s;
  __syncthreads();
  for (int off = 1; off < 256; off <<= 1) {
    int x = (t >= off) ? sh[t - off] : 0;
    __syncthreads();
    sh[t] += x;
    __syncthreads();
  }
  int run = sh[t] - s;
#pragma unroll
  for (int j = 0; j < 4; j++) { if (base + j < n) out[base + j] = run; run += v[j]; }
  if (t == 255) bsums[blockIdx.x] = sh[255];
}

__global__ void scan_carry(int* bsums, int nb, int* sentinel) {
  if (threadIdx.x == 0 && blockIdx.x == 0) {
    int run = 0;
    for (int b = 0; b < nb; b++) { int x = bsums[b]; bsums[b] = run; run += x; }
    *sentinel = run;
  }
}

__global__ void scan_add(int* __restrict__ out, const int* __restrict__ bsums, int n) {
  int base = blockIdx.x * 1024 + threadIdx.x * 4;
  int c = bsums[blockIdx.x];
#pragma unroll
  for (int j = 0; j < 4; j++) if (base + j < n) out[base + j] += c;
}

__global__ void copy_k(const int* __restrict__ in, int* __restrict__ out, int n) {
  int i = blockIdx.x * blockDim.x + threadIdx.x;
  if (i < n) out[i] = in[i];
}

// ----------------------- batched pass A: logits into global CSR positions
// a_s = AS[s + soff][t*H + h]; a_d = AS[d + doff][(5+t)*H + h]  (ld = 80 or 16)
struct PassAJobs {
  const int* src[5]; const int* dst[5]; const int* perm[5];
  const float* ea[5];
  const float* w32[5]; const float* cv[5];
  int soff[5], doff[5];
  int E[5]; int bpref[6];
};

template <int H, int LD>
__global__ __launch_bounds__(256) void pass_a_b(PassAJobs J, const float* __restrict__ AS,
                                                float* __restrict__ logits) {
  int b = blockIdx.x;
  int t = 0;
  while (t < 4 && b >= J.bpref[t + 1]) t++;
  __shared__ float w[H][32];
  __shared__ float cc[H];
  for (int i = threadIdx.x; i < H * 32; i += 256) w[i >> 5][i & 31] = J.w32[t][i];
  if (threadIdx.x < H) cc[threadIdx.x] = J.cv[t][threadIdx.x];
  __syncthreads();
  int e = (b - J.bpref[t]) * 256 + threadIdx.x;
  if (e >= J.E[t]) return;
  int s = J.src[t][e], d = J.dst[t][e], pe = J.perm[t][e];
  const float* asp = AS + (size_t)(s + J.soff[t]) * LD + t * H;
  const float* adp = AS + (size_t)(d + J.doff[t]) * LD + (5 + t) * H;
  float x[32];
  const float4* p = (const float4*)(J.ea[t] + (size_t)e * 32);
#pragma unroll
  for (int i = 0; i < 8; i++) {
    float4 v = p[i];
    x[4 * i] = v.x; x[4 * i + 1] = v.y; x[4 * i + 2] = v.z; x[4 * i + 3] = v.w;
  }
#pragma unroll
  for (int h = 0; h < H; h++) {
    float a = cc[h];
#pragma unroll
    for (int k = 0; k < 32; k++) a += x[k] * w[h][k];
    float v = a + asp[h] + adp[h];
    v = v > 0.f ? v : 0.2f * v;
    logits[(size_t)pe * H + h] = v;
  }
}

// ------- segment softmax per (dst,relation) sub-segment, in place -> alpha
template <int H>
__global__ void softmax_k(const int* __restrict__ rs, float* __restrict__ lg) {
  int g = (int)((blockIdx.x * (size_t)blockDim.x + threadIdx.x) >> 6);
  int lane = threadIdx.x & 63;
  if (g >= kSeg) return;
  int start = rs[g], end = rs[g + 1];
  int n = (end - start) * H;
  if (n == 0) return;
  float* L = lg + (size_t)start * H;
  float m = -3.0e38f;
  for (int idx = lane; idx < n; idx += 64) m = fmaxf(m, L[idx]);
  if (H == 8) {
    m = fmaxf(m, __shfl_xor(m, 8));
    m = fmaxf(m, __shfl_xor(m, 16));
    m = fmaxf(m, __shfl_xor(m, 32));
  } else {
#pragma unroll
    for (int off = 1; off < 64; off <<= 1) m = fmaxf(m, __shfl_xor(m, off));
  }
  float s = 0.f;
  for (int idx = lane; idx < n; idx += 64) {
    float ex = __expf(L[idx] - m);
    L[idx] = ex;
    s += ex;
  }
  if (H == 8) {
    s += __shfl_xor(s, 8);
    s += __shfl_xor(s, 16);
    s += __shfl_xor(s, 32);
  } else {
#pragma unroll
    for (int off = 1; off < 64; off <<= 1) s += __shfl_xor(s, off);
  }
  float inv = 1.f / (s + 1e-16f);
  for (int idx = lane; idx < n; idx += 64) L[idx] *= inv;
}

// --------------- unified gather: agg[g] = sum over node's sub-segments of alpha*xs
template <int H>
__global__ void gat_gather_u(const int* __restrict__ rs, const int* __restrict__ ssrc,
                             const float* __restrict__ alpha,
                             const unsigned short* __restrict__ xs,
                             float* __restrict__ agg) {
  int g = (int)((blockIdx.x * (size_t)blockDim.x + threadIdx.x) >> 6);
  int lane = threadIdx.x & 63;
  if (g >= kNTot) return;
  int start, end;
  if (g < 50000)      { start = rs[3 * g];              end = rs[3 * g + 3]; }
  else if (g < 51000) { int m = g - 50000; start = rs[150000 + m]; end = rs[150001 + m]; }
  else                { int j = g - 51000; start = rs[151000 + j]; end = rs[151001 + j]; }
  int deg = end - start;
  int l16 = lane & 15, quad = lane >> 4;
  int h = (H == 8) ? (l16 >> 1) : 0;
  float acc[8] = {0.f, 0.f, 0.f, 0.f, 0.f, 0.f, 0.f, 0.f};
  for (int base = 0; base < deg; base += 64) {
    int nchunk = deg - base; if (nchunk > 64) nchunk = 64;
    int sv = (lane < nchunk) ? ssrc[start + base + lane] : 0;
    for (int i = 0; i < nchunk; i += 4) {
      int e = i + quad;
      bool act = e < nchunk;
      int s = __shfl(sv, act ? e : 0);
      float w = act ? alpha[(size_t)(start + base + e) * H + h] : 0.f;
      int4 raw = *(const int4*)(xs + (size_t)s * HID + l16 * 8);
      unsigned ua[4] = {(unsigned)raw.x, (unsigned)raw.y, (unsigned)raw.z, (unsigned)raw.w};
#pragma unroll
      for (int j = 0; j < 4; j++) {
        acc[2 * j]     += w * __uint_as_float(ua[j] << 16);
        acc[2 * j + 1] += w * __uint_as_float(ua[j] & 0xFFFF0000u);
      }
    }
  }
#pragma unroll
  for (int j = 0; j < 8; j++) {
    acc[j] += __shfl_xor(acc[j], 16);
    acc[j] += __shfl_xor(acc[j], 32);
  }
  if (quad == 0) {
    float* p = agg + (size_t)g * HID + l16 * 8;
    *(float4*)p = make_float4(acc[0], acc[1], acc[2], acc[3]);
    *(float4*)(p + 4) = make_float4(acc[4], acc[5], acc[6], acc[7]);
  }
}

// ------------------------------------------------- BatchNorm column stats
__global__ void colstats_b(const float* __restrict__ x, float* __restrict__ stats) {
  static constexpr int bpref[4] = {0, 384, 400, 448};
  static constexpr int rowoff[4] = {0, 50000, 51000, 56000};
  int b = blockIdx.x;
  int t = 0;
  while (t < 2 && b >= bpref[t + 1]) t++;
  int bl = b - bpref[t], nb = bpref[t + 1] - bpref[t];
  int tid = threadIdx.x;
  int col = tid & 127, half = tid >> 7;
  float s = 0.f, q = 0.f;
  for (int r = rowoff[t] + bl * 2 + half; r < rowoff[t + 1]; r += nb * 2) {
    float v = x[(size_t)r * HID + col];
    s += v; q += v * v;
  }
  __shared__ float ls[256], lq[256];
  ls[tid] = s; lq[tid] = q;
  __syncthreads();
  if (tid < 128) {
    s = ls[tid] + ls[tid + 128];
    q = lq[tid] + lq[tid + 128];
    unsafeAtomicAdd(&stats[t * 256 + col], s);
    unsafeAtomicAdd(&stats[t * 256 + 128 + col], q);
  }
}

// --- BN apply + ReLU + residual: fp32 agg (in-place -> new x) + bf16 shadow
__global__ void bn_apply_b(float* __restrict__ agg, const float* __restrict__ xold,
                           unsigned short* __restrict__ xnb, const float* __restrict__ stats,
                           const float* __restrict__ gammaL, const float* __restrict__ betaL,
                           int relu) {
  size_t i = blockIdx.x * (size_t)blockDim.x + threadIdx.x;
  if (i >= (size_t)kNTot * 32) return;
  int row = (int)(i >> 5);
  int t = (row < 50000) ? 0 : (row < 51000 ? 1 : 2);
  float invN = (t == 0) ? (1.f / 50000.f) : (t == 1 ? (1.f / 1000.f) : (1.f / 5000.f));
  const float* st = stats + t * 256;
  const float* gm = gammaL + t * HID;
  const float* bt = betaL + t * HID;
  int c4 = ((int)(i & 31)) * 4;
  float4 av = ((const float4*)agg)[i];
  float4 xv = ((const float4*)xold)[i];
  float a[4] = {av.x, av.y, av.z, av.w};
  float xo[4] = {xv.x, xv.y, xv.z, xv.w};
  float o[4];
#pragma unroll
  for (int j = 0; j < 4; j++) {
    int c = c4 + j;
    float mu = st[c] * invN;
    float var = st[128 + c] * invN - mu * mu;
    float g = gm[c] * rsqrtf(var + 1e-5f);
    float v = (a[j] - mu) * g + bt[c];
    if (relu) v = fmaxf(v, 0.f);
    o[j] = v + xo[j];
  }
  ((float4*)agg)[i] = make_float4(o[0], o[1], o[2], o[3]);
  ((ushort4*)xnb)[i] = make_ushort4(f2b(o[0]), f2b(o[1]), f2b(o[2]), f2b(o[3]));
}

// ============================================================== host driver
extern "C" void kernel_launch(void* const* d_in, const int* in_sizes, int n_in,
                              void* d_out, int out_size, void* d_ws, size_t ws_size,
                              hipStream_t stream) {
  const float* x_in[3] = {(const float*)d_in[0], (const float*)d_in[1], (const float*)d_in[2]};
  const int* ei[5];
  const float* ea[5];
  for (int t = 0; t < 5; t++) {
    ei[t] = (const int*)d_in[3 + 2 * t];
    ea[t] = (const float*)d_in[4 + 2 * t];
  }
  const float* Wn[3]  = {(const float*)d_in[13], (const float*)d_in[15], (const float*)d_in[17]};
  const float* bnb[3] = {(const float*)d_in[14], (const float*)d_in[16], (const float*)d_in[18]};
  const float* Wep   = (const float*)d_in[19];
  const float* bep   = (const float*)d_in[20];
  const float* Wg    = (const float*)d_in[21];
  const float* att_s = (const float*)d_in[22];
  const float* att_d = (const float*)d_in[23];
  const float* Wge   = (const float*)d_in[24];
  const float* att_e = (const float*)d_in[25];
  // d_in[26] = bg: cancelled exactly by BatchNorm mean-subtraction; unused.
  const float* gamma = (const float*)d_in[27];
  const float* beta  = (const float*)d_in[28];
  const float* Wo    = (const float*)d_in[29];
  const float* bo    = (const float*)d_in[30];

  float* ws = (float*)d_ws;
  size_t off = 0;
  auto alloc = [&](size_t n) { size_t o = off; off += (n + 255) & ~(size_t)255; return o; };
  auto allocb = [&](size_t n) { return alloc((n + 1) / 2); };

  float* bufA = ws + alloc((size_t)kNTot * HID);   // fp32 x (residual chain)
  float* bufB = ws + alloc((size_t)kNTot * HID);   // fp32 agg / next x
  unsigned short* xcurb = (unsigned short*)(ws + allocb((size_t)kNTot * HID));
  unsigned short* xs_all = (unsigned short*)(ws + allocb((size_t)kRTot * HID));
  unsigned short* WgT  = (unsigned short*)(ws + allocb((size_t)15 * HID * HID));
  unsigned short* WoT  = (unsigned short*)(ws + allocb((size_t)HID * HID));
  unsigned short* WnT_op  = (unsigned short*)(ws + allocb((size_t)HID * 64));
  unsigned short* WnT_ma  = (unsigned short*)(ws + allocb((size_t)HID * 32));
  unsigned short* WnT_job = (unsigned short*)(ws + allocb((size_t)HID * 32));
  unsigned short* VbT  = (unsigned short*)(ws + allocb((size_t)3 * 80 * HID));
  float* Sv     = ws + alloc((size_t)15 * 8 * HID);
  float* Dv     = ws + alloc((size_t)15 * 8 * HID);
  float* w32    = ws + alloc((size_t)15 * 8 * 32);
  float* cv     = ws + alloc((size_t)15 * 8);
  float* stats  = ws + alloc((size_t)3 * 256);
  float* ASbuf  = ws + alloc((size_t)kNTot * 80);
  float* logits = ws + alloc((size_t)kETot * 8 + 64);
  int* rs_all   = (int*)(ws + alloc((size_t)kSeg + 8));
  int* perm_all = (int*)(ws + alloc((size_t)kETot));
  int* ssrc_all = (int*)(ws + alloc((size_t)kETot));
  // aliases: xinb_* live inside xs_all (consumed before xs_all is written);
  // cnt/cursor/bsums live inside logits (CSR build precedes first logit write)
  unsigned short* xinb_op  = xs_all;                          // 3.2M ushorts
  unsigned short* xinb_ma  = xs_all + 3200000;                // 32k ushorts
  unsigned short* xinb_job = xs_all + 3232000;                // 160k ushorts
  int* cnt    = (int*)logits;
  int* cursor = (int*)(logits + 156032);
  int* bsums  = (int*)(logits + 312064);
  (void)ws_size; (void)in_sizes; (void)n_in; (void)out_size;

  float* xcur = bufA;
  float* agg  = bufB;

  // -------- unified CSR over (dst,relation) sub-segments, built once
  EdgeJobs EJ;
  for (int t = 0; t < 5; t++) { EJ.src[t] = ei[t]; EJ.dst[t] = ei[t] + kEsz[t]; }
  hipMemsetAsync(cnt, 0, (size_t)kSeg * 4, stream);
  hist_b<<<(kETot + 255) / 256, 256, 0, stream>>>(EJ, cnt);
  int nb = (kSeg + 1023) / 1024;
  scan_blocks<<<nb, 256, 0, stream>>>(cnt, rs_all, bsums, kSeg);
  scan_carry<<<1, 64, 0, stream>>>(bsums, nb, rs_all + kSeg);
  scan_add<<<nb, 256, 0, stream>>>(rs_all, bsums, kSeg);
  copy_k<<<(kSeg + 255) / 256, 256, 0, stream>>>(rs_all, cursor, kSeg);
  scatter_b<<<(kETot + 255) / 256, 256, 0, stream>>>(EJ, cursor, perm_all, ssrc_all);

  // -------- bf16 conversions
  conv_pad<<<(kNOp * 64 + 255) / 256, 256, 0, stream>>>(x_in[0], xinb_op, kNOp, 64, 64);
  conv_pad<<<(kNMa * 32 + 255) / 256, 256, 0, stream>>>(x_in[1], xinb_ma, kNMa, 32, 32);
  conv_pad<<<(kNJob * 32 + 255) / 256, 256, 0, stream>>>(x_in[2], xinb_job, kNJob, 16, 32);
  transpose_w<<<(HID * 64 + 255) / 256, 256, 0, stream>>>(Wn[0], WnT_op, 64, HID, 64, 1);
  transpose_w<<<(HID * 32 + 255) / 256, 256, 0, stream>>>(Wn[1], WnT_ma, 32, HID, 32, 1);
  transpose_w<<<(HID * 32 + 255) / 256, 256, 0, stream>>>(Wn[2], WnT_job, 16, HID, 32, 1);
  transpose_w<<<(15 * HID * HID + 255) / 256, 256, 0, stream>>>(Wg, WgT, HID, HID, HID, 15);
  transpose_w<<<(HID * HID + 255) / 256, 256, 0, stream>>>(Wo, WoT, HID, HID, HID, 1);
  fold_kernel<<<120, 128, 0, stream>>>(Wg, att_s, att_d, Wge, att_e, Wep, bep,
                                       Sv, Dv, w32, cv);
  build_vb<<<(3 * 80 * HID + 255) / 256, 256, 0, stream>>>(Sv, Dv, VbT);

  // -------- node input projections (fp32 x + bf16 shadow)
  gemm_mfma<2><<<((kNOp + 15) / 16 + 3) / 4, 256, 0, stream>>>(
      xinb_op, WnT_op, bnb[0], xcur, xcurb, kNOp);
  gemm_mfma<1><<<((kNMa + 15) / 16 + 3) / 4, 256, 0, stream>>>(
      xinb_ma, WnT_ma, bnb[1], xcur + (size_t)50000 * HID, xcurb + (size_t)50000 * HID, kNMa);
  gemm_mfma<1><<<((kNJob + 15) / 16 + 3) / 4, 256, 0, stream>>>(
      xinb_job, WnT_job, bnb[2], xcur + (size_t)51000 * HID, xcurb + (size_t)51000 * HID, kNJob);

  static constexpr int gemmBpref[6]  = {0, 782, 1564, 1580, 1659, 2441};
  static constexpr int passABpref[6] = {0, 587, 978, 1565, 1956, 2347};
  static constexpr int nsRel[5] = {50000, 50000, 1000, 5000, 50000};

  for (int l = 0; l < 3; l++) {
    int H = (l < 2) ? 8 : 1;

    GemmJobs GJ;
    for (int t = 0; t < 5; t++) {
      int lt = l * 5 + t;
      GJ.A[t]  = xcurb + (size_t)kNodeOff[kSrcT[t]] * HID;
      GJ.Bt[t] = WgT + (size_t)lt * HID * HID;
      GJ.Cb[t] = xs_all + (size_t)kRoff[t] * HID;
      GJ.M[t] = nsRel[t];
      GJ.bpref[t] = gemmBpref[t];
    }
    GJ.bpref[5] = gemmBpref[5];
    gemm_batched<<<gemmBpref[5], 256, 0, stream>>>(GJ);

    // a_s/a_d for all (relation, head) via one MFMA GEMM
    int asBlocks = ((kNTot + 15) / 16 + 3) / 4;
    if (H == 8)
      gemm_as<80><<<asBlocks, 256, 0, stream>>>(xcurb, VbT + (size_t)l * 80 * HID, ASbuf, kNTot);
    else
      gemm_as<16><<<asBlocks, 256, 0, stream>>>(xcurb, VbT + (size_t)l * 80 * HID, ASbuf, kNTot);

    PassAJobs PJ;
    for (int t = 0; t < 5; t++) {
      int lt = l * 5 + t;
      PJ.src[t] = ei[t]; PJ.dst[t] = ei[t] + kEsz[t];
      PJ.perm[t] = perm_all + kEoff[t];
      PJ.ea[t] = ea[t];
      PJ.w32[t] = w32 + (size_t)lt * 8 * 32;
      PJ.cv[t]  = cv + (size_t)lt * 8;
      PJ.soff[t] = kNodeOff[kSrcT[t]];
      PJ.doff[t] = kNodeOff[kDstT[t]];
      PJ.E[t] = kEsz[t];
      PJ.bpref[t] = passABpref[t];
    }
    PJ.bpref[5] = passABpref[5];
    if (H == 8) pass_a_b<8, 80><<<passABpref[5], 256, 0, stream>>>(PJ, ASbuf, logits);
    else        pass_a_b<1, 16><<<passABpref[5], 256, 0, stream>>>(PJ, ASbuf, logits);

    if (H == 8) {
      softmax_k<8><<<((size_t)kSeg * 64 + 255) / 256, 256, 0, stream>>>(rs_all, logits);
      gat_gather_u<8><<<((size_t)kNTot * 64 + 255) / 256, 256, 0, stream>>>(
          rs_all, ssrc_all, logits, xs_all, agg);
    } else {
      softmax_k<1><<<((size_t)kSeg * 64 + 255) / 256, 256, 0, stream>>>(rs_all, logits);
      gat_gather_u<1><<<((size_t)kNTot * 64 + 255) / 256, 256, 0, stream>>>(
          rs_all, ssrc_all, logits, xs_all, agg);
    }

    hipMemsetAsync(stats, 0, 3 * 256 * 4, stream);
    colstats_b<<<448, 256, 0, stream>>>(agg, stats);
    bn_apply_b<<<(unsigned)(((size_t)kNTot * 32 + 255) / 256), 256, 0, stream>>>(
        agg, xcur, xcurb, stats, gamma + (size_t)l * 3 * HID, beta + (size_t)l * 3 * HID,
        (l < 2) ? 1 : 0);
    float* tmp = xcur; xcur = agg; agg = tmp;   // agg now holds new fp32 x
  }

  gemm_mfma<4><<<((kNOp + 15) / 16 + 3) / 4, 256, 0, stream>>>(
      xcurb, WoT, bo, (float*)d_out, nullptr, kNOp);
}